// Round 1
// baseline (864.901 us; speedup 1.0000x reference)
//
#include <hip/hip_runtime.h>
#include <hip/hip_bf16.h>

// ---------------------------------------------------------------------------
// Mamba encoder fwd: B=2, L=1024, D=512, E=1024, N=16, R=32, 6 layers.
// Inputs fp32 (probe-confirmed; dynamic dtype kept). Output fp32.
// GEMMs: split-bf16 (hi/lo, 3 MFMAs). in_proj uses 128x128 tile (LDS-read
// balanced, ~91% MFMA ratio); others 64x64. Weights pre-split once (1 kernel).
// Scan: chunked 64 x 16, lane axis = e, batch-preloaded operands; stage2
// batched 8-deep to hide load latency.
// ws_size = 256 MiB (fill-evidence); we use ~115 MB.
// ---------------------------------------------------------------------------

typedef __attribute__((ext_vector_type(8))) short bf16x8;
typedef __attribute__((ext_vector_type(4))) float f32x4;

__device__ __forceinline__ float bf2f(unsigned short u) {
    unsigned int x = ((unsigned int)u) << 16;
    return __builtin_bit_cast(float, x);
}
__device__ __forceinline__ unsigned short f2bf(float f) {
    __hip_bfloat16 h = __float2bfloat16(f);   // RNE
    return __builtin_bit_cast(unsigned short, h);
}
__device__ __forceinline__ float ldin(const void* p, size_t i, int isbf) {
    return isbf ? bf2f(((const unsigned short*)p)[i]) : ((const float*)p)[i];
}
__device__ __forceinline__ float softplus_f(float x) {
    return (x > 20.f) ? x : log1pf(__expf(x));
}
__device__ __forceinline__ void split2(float x, unsigned short& h, unsigned short& l) {
    h = f2bf(x);
    l = f2bf(x - bf2f(h));   // == 0 when x is exactly bf16
}

// --------- all-weights pre-split (+ dtype flag publish), one kernel ---------
#define S1 (6*2048*512)
#define S2 (6*512*1024)
#define S3 (6*64*1024)
#define S4 (6*1024*32)
__global__ __launch_bounds__(256) void wsplit_all(
    const void* __restrict__ ipw, const void* __restrict__ ow,
    const void* __restrict__ xpw, const void* __restrict__ dtw,
    const void* __restrict__ Dw,
    unsigned short* __restrict__ h1, unsigned short* __restrict__ l1,
    unsigned short* __restrict__ h2, unsigned short* __restrict__ l2,
    unsigned short* __restrict__ h3, unsigned short* __restrict__ l3,
    unsigned short* __restrict__ h4, unsigned short* __restrict__ l4,
    int* __restrict__ flag)
{
    int g = blockIdx.x * 256 + threadIdx.x;
    const int isbf = (*(const unsigned int*)Dw == 0x3F800000u) ? 0 : 1;
    if (g == 0) *flag = isbf;
    const void* src; unsigned short *dh, *dl; int i;
    if (g < S1)                { src = ipw; dh = h1; dl = l1; i = g; }
    else if (g < S1+S2)        { src = ow;  dh = h2; dl = l2; i = g - S1; }
    else if (g < S1+S2+S3)     { src = xpw; dh = h3; dl = l3; i = g - S1 - S2; }
    else if (g < S1+S2+S3+S4)  { src = dtw; dh = h4; dl = l4; i = g - S1 - S2 - S3; }
    else return;
    unsigned short hh, ll;
    split2(ldin(src, i, isbf), hh, ll);
    dh[i] = hh; dl[i] = ll;
}

// ------------------ GEMM 128x128 tile (in_proj): C = A * W^T ----------------
// A,W pre-split bf16 hi/lo.  BK=32, 256 threads (4 waves, 2x2, each 64x64).
__global__ __launch_bounds__(256) void gemm128(
    const unsigned short* __restrict__ Ah, const unsigned short* __restrict__ Al,
    int lda,
    const unsigned short* __restrict__ Wh, const unsigned short* __restrict__ Wl,
    long woff,
    float* __restrict__ Cf, int N, int K)
{
    __shared__ __align__(16) unsigned short As[2][128][40];
    __shared__ __align__(16) unsigned short Ws[2][128][40];

    const int m0 = blockIdx.x * 128, n0 = blockIdx.y * 128;
    const int t = threadIdx.x, lane = t & 63, wave = t >> 6;
    const int wm = (wave & 1) * 64, wn = (wave >> 1) * 64;
    const int srow = t >> 1, scol = (t & 1) * 16;

    const unsigned short* ah = Ah + (size_t)(m0 + srow) * lda + scol;
    const unsigned short* al = Al + (size_t)(m0 + srow) * lda + scol;
    const unsigned short* wh = Wh + woff + (size_t)(n0 + srow) * K + scol;
    const unsigned short* wl = Wl + woff + (size_t)(n0 + srow) * K + scol;

    f32x4 acc[4][4] = {};
    const int fm = lane & 15, fk = (lane >> 4) * 8;

    for (int k0 = 0; k0 < K; k0 += 32) {
        __syncthreads();
        *(uint4*)(&As[0][srow][scol])     = *(const uint4*)(ah + k0);
        *(uint4*)(&As[0][srow][scol + 8]) = *(const uint4*)(ah + k0 + 8);
        *(uint4*)(&As[1][srow][scol])     = *(const uint4*)(al + k0);
        *(uint4*)(&As[1][srow][scol + 8]) = *(const uint4*)(al + k0 + 8);
        *(uint4*)(&Ws[0][srow][scol])     = *(const uint4*)(wh + k0);
        *(uint4*)(&Ws[0][srow][scol + 8]) = *(const uint4*)(wh + k0 + 8);
        *(uint4*)(&Ws[1][srow][scol])     = *(const uint4*)(wl + k0);
        *(uint4*)(&Ws[1][srow][scol + 8]) = *(const uint4*)(wl + k0 + 8);
        __syncthreads();

        bf16x8 a_h[4], a_l[4], w_h[4], w_l[4];
#pragma unroll
        for (int i = 0; i < 4; ++i) {
            a_h[i] = *(const bf16x8*)(&As[0][wm + i * 16 + fm][fk]);
            a_l[i] = *(const bf16x8*)(&As[1][wm + i * 16 + fm][fk]);
            w_h[i] = *(const bf16x8*)(&Ws[0][wn + i * 16 + fm][fk]);
            w_l[i] = *(const bf16x8*)(&Ws[1][wn + i * 16 + fm][fk]);
        }
#pragma unroll
        for (int mi = 0; mi < 4; ++mi)
#pragma unroll
            for (int ni = 0; ni < 4; ++ni) {
                acc[mi][ni] = __builtin_amdgcn_mfma_f32_16x16x32_bf16(
                    a_h[mi], w_h[ni], acc[mi][ni], 0, 0, 0);
                acc[mi][ni] = __builtin_amdgcn_mfma_f32_16x16x32_bf16(
                    a_h[mi], w_l[ni], acc[mi][ni], 0, 0, 0);
                acc[mi][ni] = __builtin_amdgcn_mfma_f32_16x16x32_bf16(
                    a_l[mi], w_h[ni], acc[mi][ni], 0, 0, 0);
            }
    }

    const int col = lane & 15, rb = (lane >> 4) * 4;
#pragma unroll
    for (int mi = 0; mi < 4; ++mi)
#pragma unroll
        for (int ni = 0; ni < 4; ++ni)
#pragma unroll
            for (int r = 0; r < 4; ++r) {
                int gm = m0 + wm + mi * 16 + rb + r;
                int gn = n0 + wn + ni * 16 + col;
                Cf[(size_t)gm * N + gn] = acc[mi][ni][r];
            }
}

// ----------------------- GEMM 64x64 tile: C = A * W^T -----------------------
// Optional split-K via blockIdx.z.  acc += Ah*Wh + Ah*Wl + Al*Wh.
template <int ACT>
__global__ __launch_bounds__(256) void gemm_hl(
    const unsigned short* __restrict__ Ah, const unsigned short* __restrict__ Al,
    int lda,
    const unsigned short* __restrict__ Wh, const unsigned short* __restrict__ Wl,
    long woff,
    float* __restrict__ Cf, long zstride,
    const void* __restrict__ bias, long boff, const int* __restrict__ flag,
    int N, int K, int Kc)
{
    const int isbf = *flag;
    __shared__ __align__(16) unsigned short As[2][64][40];
    __shared__ __align__(16) unsigned short Ws[2][64][40];

    const int m0 = blockIdx.x * 64, n0 = blockIdx.y * 64;
    const int kb = blockIdx.z * Kc;
    const int t = threadIdx.x;
    const int lane = t & 63, wave = t >> 6;
    const int wm = (wave & 1) * 32, wn = (wave >> 1) * 32;
    const int srow = t >> 2, scol = (t & 3) * 8;

    const unsigned short* ah = Ah + (size_t)(m0 + srow) * lda + scol;
    const unsigned short* al = Al + (size_t)(m0 + srow) * lda + scol;
    const unsigned short* wh = Wh + woff + (size_t)(n0 + srow) * K + scol;
    const unsigned short* wl = Wl + woff + (size_t)(n0 + srow) * K + scol;

    f32x4 acc[2][2] = {};

    for (int k0 = kb; k0 < kb + Kc; k0 += 32) {
        __syncthreads();
        *(uint4*)(&As[0][srow][scol]) = *(const uint4*)(ah + k0);
        *(uint4*)(&As[1][srow][scol]) = *(const uint4*)(al + k0);
        *(uint4*)(&Ws[0][srow][scol]) = *(const uint4*)(wh + k0);
        *(uint4*)(&Ws[1][srow][scol]) = *(const uint4*)(wl + k0);
        __syncthreads();

        const int fm = lane & 15, fk = (lane >> 4) * 8;
        bf16x8 a0h = *(const bf16x8*)(&As[0][wm + fm][fk]);
        bf16x8 a1h = *(const bf16x8*)(&As[0][wm + 16 + fm][fk]);
        bf16x8 w0h = *(const bf16x8*)(&Ws[0][wn + fm][fk]);
        bf16x8 w1h = *(const bf16x8*)(&Ws[0][wn + 16 + fm][fk]);
        bf16x8 a0l = *(const bf16x8*)(&As[1][wm + fm][fk]);
        bf16x8 a1l = *(const bf16x8*)(&As[1][wm + 16 + fm][fk]);
        bf16x8 w0l = *(const bf16x8*)(&Ws[1][wn + fm][fk]);
        bf16x8 w1l = *(const bf16x8*)(&Ws[1][wn + 16 + fm][fk]);

        acc[0][0] = __builtin_amdgcn_mfma_f32_16x16x32_bf16(a0h, w0h, acc[0][0], 0, 0, 0);
        acc[0][1] = __builtin_amdgcn_mfma_f32_16x16x32_bf16(a0h, w1h, acc[0][1], 0, 0, 0);
        acc[1][0] = __builtin_amdgcn_mfma_f32_16x16x32_bf16(a1h, w0h, acc[1][0], 0, 0, 0);
        acc[1][1] = __builtin_amdgcn_mfma_f32_16x16x32_bf16(a1h, w1h, acc[1][1], 0, 0, 0);
        acc[0][0] = __builtin_amdgcn_mfma_f32_16x16x32_bf16(a0h, w0l, acc[0][0], 0, 0, 0);
        acc[0][1] = __builtin_amdgcn_mfma_f32_16x16x32_bf16(a0h, w1l, acc[0][1], 0, 0, 0);
        acc[1][0] = __builtin_amdgcn_mfma_f32_16x16x32_bf16(a1h, w0l, acc[1][0], 0, 0, 0);
        acc[1][1] = __builtin_amdgcn_mfma_f32_16x16x32_bf16(a1h, w1l, acc[1][1], 0, 0, 0);
        acc[0][0] = __builtin_amdgcn_mfma_f32_16x16x32_bf16(a0l, w0h, acc[0][0], 0, 0, 0);
        acc[0][1] = __builtin_amdgcn_mfma_f32_16x16x32_bf16(a0l, w1h, acc[0][1], 0, 0, 0);
        acc[1][0] = __builtin_amdgcn_mfma_f32_16x16x32_bf16(a1l, w0h, acc[1][0], 0, 0, 0);
        acc[1][1] = __builtin_amdgcn_mfma_f32_16x16x32_bf16(a1l, w1h, acc[1][1], 0, 0, 0);
    }

    float* Cp = Cf + (size_t)blockIdx.z * zstride;
    const int col = lane & 15, rb = (lane >> 4) * 4;
#pragma unroll
    for (int mi = 0; mi < 2; ++mi)
#pragma unroll
        for (int ni = 0; ni < 2; ++ni)
#pragma unroll
            for (int r = 0; r < 4; ++r) {
                int gm = m0 + wm + mi * 16 + rb + r;
                int gn = n0 + wn + ni * 16 + col;
                float v = acc[mi][ni][r];
                if (bias) v += ldin(bias, boff + gn, isbf);
                if (ACT == 1) v = softplus_f(v);
                Cp[(size_t)gm * N + gn] = v;
            }
}

// ------------- split-K reduce for x_proj + dt-operand pre-split -------------
__global__ __launch_bounds__(256) void xp_reduce(
    const float* __restrict__ Pxp, float* __restrict__ dbc,
    unsigned short* __restrict__ dth, unsigned short* __restrict__ dtl)
{
    int g = blockIdx.x * 256 + threadIdx.x;   // 131072 = 2048*64
    float s = 0.f;
#pragma unroll
    for (int z = 0; z < 8; ++z) s += Pxp[(size_t)z * 131072 + g];
    dbc[g] = s;
    int n = g & 63, t = g >> 6;
    if (n < 32) {
        unsigned short hh, ll;
        split2(s, hh, ll);
        dth[t * 32 + n] = hh; dtl[t * 32 + n] = ll;
    }
}

// ------------------- RMSNorm(h + pos) -> pre-split bf16 ---------------------
// hdyn=1: hsrc has the dynamic input dtype (layer 0, reads x); else fp32.
__global__ __launch_bounds__(256) void rmsnorm_k(
    const void* __restrict__ hsrc, int hdyn, const void* __restrict__ pos,
    const void* __restrict__ nw, const int* __restrict__ flag,
    unsigned short* __restrict__ xnh, unsigned short* __restrict__ xnl)
{
    const int isbf = *flag;
    const int row = blockIdx.x;
    const int t = threadIdx.x;
    const size_t base = (size_t)row * 512;
    float h0 = hdyn ? ldin(hsrc, base + t, isbf)       : ((const float*)hsrc)[base + t];
    float h1 = hdyn ? ldin(hsrc, base + 256 + t, isbf) : ((const float*)hsrc)[base + 256 + t];
    float v0 = h0 + ldin(pos, base + t, isbf);
    float v1 = h1 + ldin(pos, base + 256 + t, isbf);
    float ss = v0 * v0 + v1 * v1;
#pragma unroll
    for (int o = 32; o; o >>= 1) ss += __shfl_xor(ss, o, 64);
    __shared__ float sw[4];
    if ((t & 63) == 0) sw[t >> 6] = ss;
    __syncthreads();
    float tot = sw[0] + sw[1] + sw[2] + sw[3];
    float sc = rsqrtf(tot * (1.0f / 512.0f) + 1.1920929e-07f);
    float o0 = v0 * sc * ldin(nw, t, isbf);
    float o1 = v1 * sc * ldin(nw, 256 + t, isbf);
    unsigned short hh, ll;
    split2(o0, hh, ll); xnh[base + t] = hh;       xnl[base + t] = ll;
    split2(o1, hh, ll); xnh[base + 256 + t] = hh; xnl[base + 256 + t] = ll;
}

// ------- causal depthwise conv (k=4) + SiLU -> fp32 u + pre-split bf16 ------
__global__ __launch_bounds__(256) void conv_silu_k(
    const float* __restrict__ xz,
    const void* __restrict__ cw, long cwoff,
    const void* __restrict__ cb, long cboff,
    const int* __restrict__ flag,
    float* __restrict__ xi,
    unsigned short* __restrict__ xih, unsigned short* __restrict__ xil)
{
    const int isbf = *flag;
    int g = blockIdx.x * 256 + threadIdx.x;   // T*E = 2M
    int e = g & 1023;
    int l = (g >> 10) & 1023;
    int b = g >> 20;
    float acc = ldin(cb, cboff + e, isbf);
#pragma unroll
    for (int k = 0; k < 4; ++k) {
        int ls = l - 3 + k;
        if (ls >= 0)
            acc += ldin(cw, cwoff + e * 4 + k, isbf) *
                   xz[((size_t)(b * 1024 + ls)) * 2048 + e];
    }
    acc = acc / (1.f + __expf(-acc));         // SiLU
    xi[g] = acc;
    unsigned short hh, ll;
    split2(acc, hh, ll);
    xih[g] = hh; xil[g] = ll;
}

// --------------------- selective scan, chunked (64 x 16) --------------------
#define CL 16
#define NCH 64

__global__ __launch_bounds__(256) void scan_stage1(
    const float* __restrict__ dtp, const float* __restrict__ u,
    const float* __restrict__ dbc,
    const void* __restrict__ alog, long aoff, const int* __restrict__ flag,
    float* __restrict__ P, float* __restrict__ S)
{
    const int isbf = *flag;
    int g = blockIdx.x * 256 + threadIdx.x;   // 131072
    int e = g & 1023, c = (g >> 10) & (NCH - 1), b = g >> 16;
    int t0 = b * 1024 + c * CL;

    float dv[CL], uv[CL];
#pragma unroll
    for (int i = 0; i < CL; ++i) {
        dv[i] = dtp[(size_t)(t0 + i) * 1024 + e];
        uv[i] = u[(size_t)(t0 + i) * 1024 + e];
    }

    float Aen[16], Pn[16], Sn[16];
#pragma unroll
    for (int n = 0; n < 16; ++n) {
        Aen[n] = -__expf(ldin(alog, aoff + e * 16 + n, isbf));
        Pn[n] = 1.f; Sn[n] = 0.f;
    }
#pragma unroll
    for (int i = 0; i < CL; ++i) {
        float d = dv[i], du = d * uv[i];
        const float4* Bp = (const float4*)(dbc + (size_t)(t0 + i) * 64 + 32);
        float4 b0 = Bp[0], b1 = Bp[1], b2 = Bp[2], b3 = Bp[3];
        float Bt[16] = {b0.x,b0.y,b0.z,b0.w, b1.x,b1.y,b1.z,b1.w,
                        b2.x,b2.y,b2.z,b2.w, b3.x,b3.y,b3.z,b3.w};
#pragma unroll
        for (int n = 0; n < 16; ++n) {
            float a = __expf(d * Aen[n]);
            Sn[n] = a * Sn[n] + du * Bt[n];
            Pn[n] *= a;
        }
    }
    size_t ob = ((size_t)(b * NCH + c) * 16) * 1024 + e;
#pragma unroll
    for (int n = 0; n < 16; ++n) {
        P[ob + (size_t)n * 1024] = Pn[n];
        S[ob + (size_t)n * 1024] = Sn[n];
    }
}

// cross-chunk combine IN PLACE, 8-deep batched loads to hide latency.
__global__ __launch_bounds__(256) void scan_stage2(
    float* __restrict__ PH, const float* __restrict__ S)
{
    int g = blockIdx.x * 256 + threadIdx.x;   // 32768: e + 1024n + 16384b
    int e = g & 1023, n = (g >> 10) & 15, b = g >> 14;
    float H = 0.f;
    for (int cb = 0; cb < NCH; cb += 8) {
        float p[8], s[8];
#pragma unroll
        for (int j = 0; j < 8; ++j) {
            size_t idx = ((size_t)(b * NCH + cb + j) * 16 + n) * 1024 + e;
            p[j] = PH[idx]; s[j] = S[idx];
        }
#pragma unroll
        for (int j = 0; j < 8; ++j) {
            size_t idx = ((size_t)(b * NCH + cb + j) * 16 + n) * 1024 + e;
            PH[idx] = H;
            H = p[j] * H + s[j];
        }
    }
}

// final sweep: y = sum_n C*h + u*D, gate with silu(z); emit pre-split bf16.
__global__ __launch_bounds__(256) void scan_stage3(
    const float* __restrict__ dtp, const float* __restrict__ u,
    const float* __restrict__ dbc,
    const void* __restrict__ alog, long aoff,
    const void* __restrict__ Dv, long doff,
    const int* __restrict__ flag,
    const float* __restrict__ xz, const float* __restrict__ H0,
    unsigned short* __restrict__ yh, unsigned short* __restrict__ yl)
{
    const int isbf = *flag;
    int g = blockIdx.x * 256 + threadIdx.x;   // 131072
    int e = g & 1023, c = (g >> 10) & (NCH - 1), b = g >> 16;
    int t0 = b * 1024 + c * CL;

    float dv[CL], uv[CL], zv[CL];
#pragma unroll
    for (int i = 0; i < CL; ++i) {
        dv[i] = dtp[(size_t)(t0 + i) * 1024 + e];
        uv[i] = u[(size_t)(t0 + i) * 1024 + e];
        zv[i] = xz[(size_t)(t0 + i) * 2048 + 1024 + e];
    }

    float Aen[16], h[16];
    size_t ob = ((size_t)(b * NCH + c) * 16) * 1024 + e;
#pragma unroll
    for (int n = 0; n < 16; ++n) {
        Aen[n] = -__expf(ldin(alog, aoff + e * 16 + n, isbf));
        h[n] = H0[ob + (size_t)n * 1024];
    }
    float De = ldin(Dv, doff + e, isbf);
#pragma unroll
    for (int i = 0; i < CL; ++i) {
        float d = dv[i], uu = uv[i], du = d * uu;
        const float4* Bp = (const float4*)(dbc + (size_t)(t0 + i) * 64 + 32);
        float4 b0 = Bp[0], b1 = Bp[1], b2 = Bp[2], b3 = Bp[3];
        float4 c0 = Bp[4], c1 = Bp[5], c2 = Bp[6], c3 = Bp[7];
        float Bt[16] = {b0.x,b0.y,b0.z,b0.w, b1.x,b1.y,b1.z,b1.w,
                        b2.x,b2.y,b2.z,b2.w, b3.x,b3.y,b3.z,b3.w};
        float Ct[16] = {c0.x,c0.y,c0.z,c0.w, c1.x,c1.y,c1.z,c1.w,
                        c2.x,c2.y,c2.z,c2.w, c3.x,c3.y,c3.z,c3.w};
        float y = 0.f;
#pragma unroll
        for (int n = 0; n < 16; ++n) {
            float a = __expf(d * Aen[n]);
            h[n] = a * h[n] + du * Bt[n];
            y += h[n] * Ct[n];
        }
        float sz = zv[i] / (1.f + __expf(-zv[i]));
        float yv = (y + uu * De) * sz;
        unsigned short hh, ll;
        split2(yv, hh, ll);
        yh[(size_t)(t0 + i) * 1024 + e] = hh;
        yl[(size_t)(t0 + i) * 1024 + e] = ll;
    }
}

// ------------------------------- launcher -----------------------------------
extern "C" void kernel_launch(void* const* d_in, const int* in_sizes, int n_in,
                              void* d_out, int out_size, void* d_ws, size_t ws_size,
                              hipStream_t stream)
{
    const void* x    = d_in[0];
    const void* pos  = d_in[1];
    const void* nw   = d_in[2];
    const void* ipw  = d_in[3];   // (6,2048,512)
    const void* cw   = d_in[4];   // (6,1024,4)
    const void* cb   = d_in[5];   // (6,1024)
    const void* xpw  = d_in[6];   // (6,64,1024)
    const void* dtw  = d_in[7];   // (6,1024,32)
    const void* dtb  = d_in[8];   // (6,1024)
    const void* alog = d_in[9];   // (6,1024,16)
    const void* Dw   = d_in[10];  // (6,1024)
    const void* ow   = d_in[11];  // (6,512,1024)

    char* w = (char*)d_ws;
    auto take = [&](size_t bytes) { char* p = w; w += (bytes + 255) & ~255ull; return p; };

    float* h    = (float*)take(2048ull * 512 * 4);
    float* xz   = (float*)take(2048ull * 2048 * 4);
    float* xi   = (float*)take(2048ull * 1024 * 4);
    float* dtf  = (float*)take(2048ull * 1024 * 4);
    float* dbc  = (float*)take(2048ull * 64 * 4);
    float* P    = (float*)take(2ull * NCH * 16 * 1024 * 4);   // 8 MB (also H0)
    float* S    = (float*)take(2ull * NCH * 16 * 1024 * 4);   // 8 MB
    float* Pxp  = (float*)take(8ull * 2048 * 64 * 4);
    unsigned short* xnh = (unsigned short*)take(2048ull * 512 * 2);
    unsigned short* xnl = (unsigned short*)take(2048ull * 512 * 2);
    unsigned short* xih = (unsigned short*)take(2048ull * 1024 * 2);
    unsigned short* xil = (unsigned short*)take(2048ull * 1024 * 2);
    unsigned short* yh  = (unsigned short*)take(2048ull * 1024 * 2);
    unsigned short* yl  = (unsigned short*)take(2048ull * 1024 * 2);
    unsigned short* dth = (unsigned short*)take(2048ull * 32 * 2);
    unsigned short* dtl = (unsigned short*)take(2048ull * 32 * 2);
    unsigned short* wip_h = (unsigned short*)take(6ull * 2048 * 512 * 2);
    unsigned short* wip_l = (unsigned short*)take(6ull * 2048 * 512 * 2);
    unsigned short* wow_h = (unsigned short*)take(6ull * 512 * 1024 * 2);
    unsigned short* wow_l = (unsigned short*)take(6ull * 512 * 1024 * 2);
    unsigned short* wxp_h = (unsigned short*)take(6ull * 64 * 1024 * 2);
    unsigned short* wxp_l = (unsigned short*)take(6ull * 64 * 1024 * 2);
    unsigned short* wdt_h = (unsigned short*)take(6ull * 1024 * 32 * 2);
    unsigned short* wdt_l = (unsigned short*)take(6ull * 1024 * 32 * 2);
    int* flag = (int*)take(256);

    wsplit_all<<<(S1 + S2 + S3 + S4 + 255) / 256, 256, 0, stream>>>(
        ipw, ow, xpw, dtw, Dw,
        wip_h, wip_l, wow_h, wow_l, wxp_h, wxp_l, wdt_h, wdt_l, flag);

    for (int l = 0; l < 6; ++l) {
        // rmsnorm(h + pos): layer 0 reads x (dynamic dtype), else fp32 h
        rmsnorm_k<<<2048, 256, 0, stream>>>(
            l == 0 ? x : (const void*)h, l == 0 ? 1 : 0, pos, nw, flag, xnh, xnl);
        // in_proj: (T,512) x (2048,512)^T -> xz (T,2048), 128x128 tile
        gemm128<<<dim3(16, 16), 256, 0, stream>>>(
            xnh, xnl, 512, wip_h, wip_l, (long)l * 2048 * 512, xz, 2048, 512);
        conv_silu_k<<<8192, 256, 0, stream>>>(xz, cw, (long)l * 4096, cb, (long)l * 1024,
                                              flag, xi, xih, xil);
        // x_proj: (T,1024) x (64,1024)^T, split-K x8 -> Pxp, then reduce
        gemm_hl<0><<<dim3(32, 1, 8), 256, 0, stream>>>(
            xih, xil, 1024, wxp_h, wxp_l, (long)l * 64 * 1024,
            Pxp, 2048l * 64, nullptr, 0, flag, 64, 1024, 128);
        xp_reduce<<<512, 256, 0, stream>>>(Pxp, dbc, dth, dtl);
        // dt_proj: (T,32) x (1024,32)^T + dt_b, softplus -> dtf (T,1024)
        gemm_hl<1><<<dim3(32, 16), 256, 0, stream>>>(
            dth, dtl, 32, wdt_h, wdt_l, (long)l * 1024 * 32,
            dtf, 0, dtb, (long)l * 1024, flag, 1024, 32, 32);
        scan_stage1<<<512, 256, 0, stream>>>(dtf, xi, dbc, alog, (long)l * 16384,
                                             flag, P, S);
        scan_stage2<<<128, 256, 0, stream>>>(P, S);
        scan_stage3<<<512, 256, 0, stream>>>(dtf, xi, dbc, alog, (long)l * 16384,
                                             Dw, (long)l * 1024, flag, xz, P, yh, yl);
        // out_proj: (T,1024) x (512,1024)^T -> h (T,512); last layer -> d_out
        float* outp = (l < 5) ? h : (float*)d_out;
        gemm_hl<0><<<dim3(32, 8), 256, 0, stream>>>(
            yh, yl, 1024, wow_h, wow_l, (long)l * 512 * 1024,
            outp, 0, nullptr, 0, flag, 512, 1024, 1024);
    }
}

// Round 2
// 845.233 us; speedup vs baseline: 1.0233x; 1.0233x over previous
//
#include <hip/hip_runtime.h>
#include <hip/hip_bf16.h>

// ---------------------------------------------------------------------------
// Mamba encoder fwd: B=2, L=1024, D=512, E=1024, N=16, R=32, 6 layers.
// Inputs fp32 (probe-confirmed; dynamic dtype kept). Output fp32.
// GEMMs: split-bf16 (hi/lo, 3 MFMAs). in_proj uses 128x128 tile; others 64x64.
// R1 change: 2-phase software pipeline (register-staged double buffer) in all
// MFMA GEMMs — issue next K-tile's global loads BEFORE current tile's
// ds_read+MFMA so the ~600cy load latency hides under compute (T14/m249).
// Scan: chunked 64 x 16. ws ~115 MB of the 256 MiB workspace.
// ---------------------------------------------------------------------------

typedef __attribute__((ext_vector_type(8))) short bf16x8;
typedef __attribute__((ext_vector_type(4))) float f32x4;

__device__ __forceinline__ float bf2f(unsigned short u) {
    unsigned int x = ((unsigned int)u) << 16;
    return __builtin_bit_cast(float, x);
}
__device__ __forceinline__ unsigned short f2bf(float f) {
    __hip_bfloat16 h = __float2bfloat16(f);   // RNE
    return __builtin_bit_cast(unsigned short, h);
}
__device__ __forceinline__ float ldin(const void* p, size_t i, int isbf) {
    return isbf ? bf2f(((const unsigned short*)p)[i]) : ((const float*)p)[i];
}
__device__ __forceinline__ float softplus_f(float x) {
    return (x > 20.f) ? x : log1pf(__expf(x));
}
__device__ __forceinline__ void split2(float x, unsigned short& h, unsigned short& l) {
    h = f2bf(x);
    l = f2bf(x - bf2f(h));   // == 0 when x is exactly bf16
}

// --------- all-weights pre-split (+ dtype flag publish), one kernel ---------
#define S1 (6*2048*512)
#define S2 (6*512*1024)
#define S3 (6*64*1024)
#define S4 (6*1024*32)
__global__ __launch_bounds__(256) void wsplit_all(
    const void* __restrict__ ipw, const void* __restrict__ ow,
    const void* __restrict__ xpw, const void* __restrict__ dtw,
    const void* __restrict__ Dw,
    unsigned short* __restrict__ h1, unsigned short* __restrict__ l1,
    unsigned short* __restrict__ h2, unsigned short* __restrict__ l2,
    unsigned short* __restrict__ h3, unsigned short* __restrict__ l3,
    unsigned short* __restrict__ h4, unsigned short* __restrict__ l4,
    int* __restrict__ flag)
{
    int g = blockIdx.x * 256 + threadIdx.x;
    const int isbf = (*(const unsigned int*)Dw == 0x3F800000u) ? 0 : 1;
    if (g == 0) *flag = isbf;
    const void* src; unsigned short *dh, *dl; int i;
    if (g < S1)                { src = ipw; dh = h1; dl = l1; i = g; }
    else if (g < S1+S2)        { src = ow;  dh = h2; dl = l2; i = g - S1; }
    else if (g < S1+S2+S3)     { src = xpw; dh = h3; dl = l3; i = g - S1 - S2; }
    else if (g < S1+S2+S3+S4)  { src = dtw; dh = h4; dl = l4; i = g - S1 - S2 - S3; }
    else return;
    unsigned short hh, ll;
    split2(ldin(src, i, isbf), hh, ll);
    dh[i] = hh; dl[i] = ll;
}

// ------------------ GEMM 128x128 tile (in_proj): C = A * W^T ----------------
// A,W pre-split bf16 hi/lo.  BK=32, 256 threads (4 waves, 2x2, each 64x64).
// 2-phase pipeline: global loads for tile k+1 issue before MFMA on tile k.
__global__ __launch_bounds__(256) void gemm128(
    const unsigned short* __restrict__ Ah, const unsigned short* __restrict__ Al,
    int lda,
    const unsigned short* __restrict__ Wh, const unsigned short* __restrict__ Wl,
    long woff,
    float* __restrict__ Cf, int N, int K)
{
    __shared__ __align__(16) unsigned short As[2][128][40];
    __shared__ __align__(16) unsigned short Ws[2][128][40];

    const int m0 = blockIdx.x * 128, n0 = blockIdx.y * 128;
    const int t = threadIdx.x, lane = t & 63, wave = t >> 6;
    const int wm = (wave & 1) * 64, wn = (wave >> 1) * 64;
    const int srow = t >> 1, scol = (t & 1) * 16;

    const unsigned short* ah = Ah + (size_t)(m0 + srow) * lda + scol;
    const unsigned short* al = Al + (size_t)(m0 + srow) * lda + scol;
    const unsigned short* wh = Wh + woff + (size_t)(n0 + srow) * K + scol;
    const unsigned short* wl = Wl + woff + (size_t)(n0 + srow) * K + scol;

    f32x4 acc[4][4] = {};
    const int fm = lane & 15, fk = (lane >> 4) * 8;

    uint4 r0, r1, r2, r3, r4, r5, r6, r7;
#define LD128(K0) do { \
        r0 = *(const uint4*)(ah + (K0));     r1 = *(const uint4*)(ah + (K0) + 8); \
        r2 = *(const uint4*)(al + (K0));     r3 = *(const uint4*)(al + (K0) + 8); \
        r4 = *(const uint4*)(wh + (K0));     r5 = *(const uint4*)(wh + (K0) + 8); \
        r6 = *(const uint4*)(wl + (K0));     r7 = *(const uint4*)(wl + (K0) + 8); \
    } while (0)
#define ST128() do { \
        *(uint4*)(&As[0][srow][scol])     = r0; *(uint4*)(&As[0][srow][scol + 8]) = r1; \
        *(uint4*)(&As[1][srow][scol])     = r2; *(uint4*)(&As[1][srow][scol + 8]) = r3; \
        *(uint4*)(&Ws[0][srow][scol])     = r4; *(uint4*)(&Ws[0][srow][scol + 8]) = r5; \
        *(uint4*)(&Ws[1][srow][scol])     = r6; *(uint4*)(&Ws[1][srow][scol + 8]) = r7; \
    } while (0)

    LD128(0);
    ST128();
    __syncthreads();

    for (int k0 = 0; k0 < K; k0 += 32) {
        const int more = (k0 + 32 < K);
        if (more) LD128(k0 + 32);            // issue next tile early (latency hides)

        bf16x8 a_h[4], a_l[4], w_h[4], w_l[4];
#pragma unroll
        for (int i = 0; i < 4; ++i) {
            a_h[i] = *(const bf16x8*)(&As[0][wm + i * 16 + fm][fk]);
            a_l[i] = *(const bf16x8*)(&As[1][wm + i * 16 + fm][fk]);
            w_h[i] = *(const bf16x8*)(&Ws[0][wn + i * 16 + fm][fk]);
            w_l[i] = *(const bf16x8*)(&Ws[1][wn + i * 16 + fm][fk]);
        }
#pragma unroll
        for (int mi = 0; mi < 4; ++mi)
#pragma unroll
            for (int ni = 0; ni < 4; ++ni) {
                acc[mi][ni] = __builtin_amdgcn_mfma_f32_16x16x32_bf16(
                    a_h[mi], w_h[ni], acc[mi][ni], 0, 0, 0);
                acc[mi][ni] = __builtin_amdgcn_mfma_f32_16x16x32_bf16(
                    a_h[mi], w_l[ni], acc[mi][ni], 0, 0, 0);
                acc[mi][ni] = __builtin_amdgcn_mfma_f32_16x16x32_bf16(
                    a_l[mi], w_h[ni], acc[mi][ni], 0, 0, 0);
            }

        if (more) {
            __syncthreads();                 // all waves done reading this tile
            ST128();                         // regs -> LDS (vmcnt drains here)
            __syncthreads();                 // writes visible
        }
    }
#undef LD128
#undef ST128

    const int col = lane & 15, rb = (lane >> 4) * 4;
#pragma unroll
    for (int mi = 0; mi < 4; ++mi)
#pragma unroll
        for (int ni = 0; ni < 4; ++ni)
#pragma unroll
            for (int r = 0; r < 4; ++r) {
                int gm = m0 + wm + mi * 16 + rb + r;
                int gn = n0 + wn + ni * 16 + col;
                Cf[(size_t)gm * N + gn] = acc[mi][ni][r];
            }
}

// ----------------------- GEMM 64x64 tile: C = A * W^T -----------------------
// Optional split-K via blockIdx.z.  acc += Ah*Wh + Ah*Wl + Al*Wh.
// Same 2-phase register-staged pipeline as gemm128.
template <int ACT>
__global__ __launch_bounds__(256) void gemm_hl(
    const unsigned short* __restrict__ Ah, const unsigned short* __restrict__ Al,
    int lda,
    const unsigned short* __restrict__ Wh, const unsigned short* __restrict__ Wl,
    long woff,
    float* __restrict__ Cf, long zstride,
    const void* __restrict__ bias, long boff, const int* __restrict__ flag,
    int N, int K, int Kc)
{
    const int isbf = *flag;
    __shared__ __align__(16) unsigned short As[2][64][40];
    __shared__ __align__(16) unsigned short Ws[2][64][40];

    const int m0 = blockIdx.x * 64, n0 = blockIdx.y * 64;
    const int kb = blockIdx.z * Kc;
    const int t = threadIdx.x;
    const int lane = t & 63, wave = t >> 6;
    const int wm = (wave & 1) * 32, wn = (wave >> 1) * 32;
    const int srow = t >> 2, scol = (t & 3) * 8;

    const unsigned short* ah = Ah + (size_t)(m0 + srow) * lda + scol;
    const unsigned short* al = Al + (size_t)(m0 + srow) * lda + scol;
    const unsigned short* wh = Wh + woff + (size_t)(n0 + srow) * K + scol;
    const unsigned short* wl = Wl + woff + (size_t)(n0 + srow) * K + scol;

    f32x4 acc[2][2] = {};

    uint4 r0, r1, r2, r3;
#define LD64(K0) do { \
        r0 = *(const uint4*)(ah + (K0)); \
        r1 = *(const uint4*)(al + (K0)); \
        r2 = *(const uint4*)(wh + (K0)); \
        r3 = *(const uint4*)(wl + (K0)); \
    } while (0)
#define ST64() do { \
        *(uint4*)(&As[0][srow][scol]) = r0; \
        *(uint4*)(&As[1][srow][scol]) = r1; \
        *(uint4*)(&Ws[0][srow][scol]) = r2; \
        *(uint4*)(&Ws[1][srow][scol]) = r3; \
    } while (0)

    LD64(kb);
    ST64();
    __syncthreads();

    for (int k0 = kb; k0 < kb + Kc; k0 += 32) {
        const int more = (k0 + 32 < kb + Kc);
        if (more) LD64(k0 + 32);             // prefetch next tile into regs

        const int fm = lane & 15, fk = (lane >> 4) * 8;
        bf16x8 a0h = *(const bf16x8*)(&As[0][wm + fm][fk]);
        bf16x8 a1h = *(const bf16x8*)(&As[0][wm + 16 + fm][fk]);
        bf16x8 w0h = *(const bf16x8*)(&Ws[0][wn + fm][fk]);
        bf16x8 w1h = *(const bf16x8*)(&Ws[0][wn + 16 + fm][fk]);
        bf16x8 a0l = *(const bf16x8*)(&As[1][wm + fm][fk]);
        bf16x8 a1l = *(const bf16x8*)(&As[1][wm + 16 + fm][fk]);
        bf16x8 w0l = *(const bf16x8*)(&Ws[1][wn + fm][fk]);
        bf16x8 w1l = *(const bf16x8*)(&Ws[1][wn + 16 + fm][fk]);

        acc[0][0] = __builtin_amdgcn_mfma_f32_16x16x32_bf16(a0h, w0h, acc[0][0], 0, 0, 0);
        acc[0][1] = __builtin_amdgcn_mfma_f32_16x16x32_bf16(a0h, w1h, acc[0][1], 0, 0, 0);
        acc[1][0] = __builtin_amdgcn_mfma_f32_16x16x32_bf16(a1h, w0h, acc[1][0], 0, 0, 0);
        acc[1][1] = __builtin_amdgcn_mfma_f32_16x16x32_bf16(a1h, w1h, acc[1][1], 0, 0, 0);
        acc[0][0] = __builtin_amdgcn_mfma_f32_16x16x32_bf16(a0h, w0l, acc[0][0], 0, 0, 0);
        acc[0][1] = __builtin_amdgcn_mfma_f32_16x16x32_bf16(a0h, w1l, acc[0][1], 0, 0, 0);
        acc[1][0] = __builtin_amdgcn_mfma_f32_16x16x32_bf16(a1h, w0l, acc[1][0], 0, 0, 0);
        acc[1][1] = __builtin_amdgcn_mfma_f32_16x16x32_bf16(a1h, w1l, acc[1][1], 0, 0, 0);
        acc[0][0] = __builtin_amdgcn_mfma_f32_16x16x32_bf16(a0l, w0h, acc[0][0], 0, 0, 0);
        acc[0][1] = __builtin_amdgcn_mfma_f32_16x16x32_bf16(a0l, w1h, acc[0][1], 0, 0, 0);
        acc[1][0] = __builtin_amdgcn_mfma_f32_16x16x32_bf16(a1l, w0h, acc[1][0], 0, 0, 0);
        acc[1][1] = __builtin_amdgcn_mfma_f32_16x16x32_bf16(a1l, w1h, acc[1][1], 0, 0, 0);

        if (more) {
            __syncthreads();
            ST64();
            __syncthreads();
        }
    }
#undef LD64
#undef ST64

    float* Cp = Cf + (size_t)blockIdx.z * zstride;
    const int col = lane & 15, rb = (lane >> 4) * 4;
#pragma unroll
    for (int mi = 0; mi < 2; ++mi)
#pragma unroll
        for (int ni = 0; ni < 2; ++ni)
#pragma unroll
            for (int r = 0; r < 4; ++r) {
                int gm = m0 + wm + mi * 16 + rb + r;
                int gn = n0 + wn + ni * 16 + col;
                float v = acc[mi][ni][r];
                if (bias) v += ldin(bias, boff + gn, isbf);
                if (ACT == 1) v = softplus_f(v);
                Cp[(size_t)gm * N + gn] = v;
            }
}

// ------------- split-K reduce for x_proj + dt-operand pre-split -------------
__global__ __launch_bounds__(256) void xp_reduce(
    const float* __restrict__ Pxp, float* __restrict__ dbc,
    unsigned short* __restrict__ dth, unsigned short* __restrict__ dtl)
{
    int g = blockIdx.x * 256 + threadIdx.x;   // 131072 = 2048*64
    float s = 0.f;
#pragma unroll
    for (int z = 0; z < 8; ++z) s += Pxp[(size_t)z * 131072 + g];
    dbc[g] = s;
    int n = g & 63, t = g >> 6;
    if (n < 32) {
        unsigned short hh, ll;
        split2(s, hh, ll);
        dth[t * 32 + n] = hh; dtl[t * 32 + n] = ll;
    }
}

// ------------------- RMSNorm(h + pos) -> pre-split bf16 ---------------------
// hdyn=1: hsrc has the dynamic input dtype (layer 0, reads x); else fp32.
__global__ __launch_bounds__(256) void rmsnorm_k(
    const void* __restrict__ hsrc, int hdyn, const void* __restrict__ pos,
    const void* __restrict__ nw, const int* __restrict__ flag,
    unsigned short* __restrict__ xnh, unsigned short* __restrict__ xnl)
{
    const int isbf = *flag;
    const int row = blockIdx.x;
    const int t = threadIdx.x;
    const size_t base = (size_t)row * 512;
    float h0 = hdyn ? ldin(hsrc, base + t, isbf)       : ((const float*)hsrc)[base + t];
    float h1 = hdyn ? ldin(hsrc, base + 256 + t, isbf) : ((const float*)hsrc)[base + 256 + t];
    float v0 = h0 + ldin(pos, base + t, isbf);
    float v1 = h1 + ldin(pos, base + 256 + t, isbf);
    float ss = v0 * v0 + v1 * v1;
#pragma unroll
    for (int o = 32; o; o >>= 1) ss += __shfl_xor(ss, o, 64);
    __shared__ float sw[4];
    if ((t & 63) == 0) sw[t >> 6] = ss;
    __syncthreads();
    float tot = sw[0] + sw[1] + sw[2] + sw[3];
    float sc = rsqrtf(tot * (1.0f / 512.0f) + 1.1920929e-07f);
    float o0 = v0 * sc * ldin(nw, t, isbf);
    float o1 = v1 * sc * ldin(nw, 256 + t, isbf);
    unsigned short hh, ll;
    split2(o0, hh, ll); xnh[base + t] = hh;       xnl[base + t] = ll;
    split2(o1, hh, ll); xnh[base + 256 + t] = hh; xnl[base + 256 + t] = ll;
}

// ------- causal depthwise conv (k=4) + SiLU -> fp32 u + pre-split bf16 ------
__global__ __launch_bounds__(256) void conv_silu_k(
    const float* __restrict__ xz,
    const void* __restrict__ cw, long cwoff,
    const void* __restrict__ cb, long cboff,
    const int* __restrict__ flag,
    float* __restrict__ xi,
    unsigned short* __restrict__ xih, unsigned short* __restrict__ xil)
{
    const int isbf = *flag;
    int g = blockIdx.x * 256 + threadIdx.x;   // T*E = 2M
    int e = g & 1023;
    int l = (g >> 10) & 1023;
    int b = g >> 20;
    float acc = ldin(cb, cboff + e, isbf);
#pragma unroll
    for (int k = 0; k < 4; ++k) {
        int ls = l - 3 + k;
        if (ls >= 0)
            acc += ldin(cw, cwoff + e * 4 + k, isbf) *
                   xz[((size_t)(b * 1024 + ls)) * 2048 + e];
    }
    acc = acc / (1.f + __expf(-acc));         // SiLU
    xi[g] = acc;
    unsigned short hh, ll;
    split2(acc, hh, ll);
    xih[g] = hh; xil[g] = ll;
}

// --------------------- selective scan, chunked (64 x 16) --------------------
#define CL 16
#define NCH 64

__global__ __launch_bounds__(256) void scan_stage1(
    const float* __restrict__ dtp, const float* __restrict__ u,
    const float* __restrict__ dbc,
    const void* __restrict__ alog, long aoff, const int* __restrict__ flag,
    float* __restrict__ P, float* __restrict__ S)
{
    const int isbf = *flag;
    int g = blockIdx.x * 256 + threadIdx.x;   // 131072
    int e = g & 1023, c = (g >> 10) & (NCH - 1), b = g >> 16;
    int t0 = b * 1024 + c * CL;

    float dv[CL], uv[CL];
#pragma unroll
    for (int i = 0; i < CL; ++i) {
        dv[i] = dtp[(size_t)(t0 + i) * 1024 + e];
        uv[i] = u[(size_t)(t0 + i) * 1024 + e];
    }

    float Aen[16], Pn[16], Sn[16];
#pragma unroll
    for (int n = 0; n < 16; ++n) {
        Aen[n] = -__expf(ldin(alog, aoff + e * 16 + n, isbf));
        Pn[n] = 1.f; Sn[n] = 0.f;
    }
#pragma unroll
    for (int i = 0; i < CL; ++i) {
        float d = dv[i], du = d * uv[i];
        const float4* Bp = (const float4*)(dbc + (size_t)(t0 + i) * 64 + 32);
        float4 b0 = Bp[0], b1 = Bp[1], b2 = Bp[2], b3 = Bp[3];
        float Bt[16] = {b0.x,b0.y,b0.z,b0.w, b1.x,b1.y,b1.z,b1.w,
                        b2.x,b2.y,b2.z,b2.w, b3.x,b3.y,b3.z,b3.w};
#pragma unroll
        for (int n = 0; n < 16; ++n) {
            float a = __expf(d * Aen[n]);
            Sn[n] = a * Sn[n] + du * Bt[n];
            Pn[n] *= a;
        }
    }
    size_t ob = ((size_t)(b * NCH + c) * 16) * 1024 + e;
#pragma unroll
    for (int n = 0; n < 16; ++n) {
        P[ob + (size_t)n * 1024] = Pn[n];
        S[ob + (size_t)n * 1024] = Sn[n];
    }
}

// cross-chunk combine IN PLACE, 8-deep batched loads to hide latency.
__global__ __launch_bounds__(256) void scan_stage2(
    float* __restrict__ PH, const float* __restrict__ S)
{
    int g = blockIdx.x * 256 + threadIdx.x;   // 32768: e + 1024n + 16384b
    int e = g & 1023, n = (g >> 10) & 15, b = g >> 14;
    float H = 0.f;
    for (int cb = 0; cb < NCH; cb += 8) {
        float p[8], s[8];
#pragma unroll
        for (int j = 0; j < 8; ++j) {
            size_t idx = ((size_t)(b * NCH + cb + j) * 16 + n) * 1024 + e;
            p[j] = PH[idx]; s[j] = S[idx];
        }
#pragma unroll
        for (int j = 0; j < 8; ++j) {
            size_t idx = ((size_t)(b * NCH + cb + j) * 16 + n) * 1024 + e;
            PH[idx] = H;
            H = p[j] * H + s[j];
        }
    }
}

// final sweep: y = sum_n C*h + u*D, gate with silu(z); emit pre-split bf16.
__global__ __launch_bounds__(256) void scan_stage3(
    const float* __restrict__ dtp, const float* __restrict__ u,
    const float* __restrict__ dbc,
    const void* __restrict__ alog, long aoff,
    const void* __restrict__ Dv, long doff,
    const int* __restrict__ flag,
    const float* __restrict__ xz, const float* __restrict__ H0,
    unsigned short* __restrict__ yh, unsigned short* __restrict__ yl)
{
    const int isbf = *flag;
    int g = blockIdx.x * 256 + threadIdx.x;   // 131072
    int e = g & 1023, c = (g >> 10) & (NCH - 1), b = g >> 16;
    int t0 = b * 1024 + c * CL;

    float dv[CL], uv[CL], zv[CL];
#pragma unroll
    for (int i = 0; i < CL; ++i) {
        dv[i] = dtp[(size_t)(t0 + i) * 1024 + e];
        uv[i] = u[(size_t)(t0 + i) * 1024 + e];
        zv[i] = xz[(size_t)(t0 + i) * 2048 + 1024 + e];
    }

    float Aen[16], h[16];
    size_t ob = ((size_t)(b * NCH + c) * 16) * 1024 + e;
#pragma unroll
    for (int n = 0; n < 16; ++n) {
        Aen[n] = -__expf(ldin(alog, aoff + e * 16 + n, isbf));
        h[n] = H0[ob + (size_t)n * 1024];
    }
    float De = ldin(Dv, doff + e, isbf);
#pragma unroll
    for (int i = 0; i < CL; ++i) {
        float d = dv[i], uu = uv[i], du = d * uu;
        const float4* Bp = (const float4*)(dbc + (size_t)(t0 + i) * 64 + 32);
        float4 b0 = Bp[0], b1 = Bp[1], b2 = Bp[2], b3 = Bp[3];
        float4 c0 = Bp[4], c1 = Bp[5], c2 = Bp[6], c3 = Bp[7];
        float Bt[16] = {b0.x,b0.y,b0.z,b0.w, b1.x,b1.y,b1.z,b1.w,
                        b2.x,b2.y,b2.z,b2.w, b3.x,b3.y,b3.z,b3.w};
        float Ct[16] = {c0.x,c0.y,c0.z,c0.w, c1.x,c1.y,c1.z,c1.w,
                        c2.x,c2.y,c2.z,c2.w, c3.x,c3.y,c3.z,c3.w};
        float y = 0.f;
#pragma unroll
        for (int n = 0; n < 16; ++n) {
            float a = __expf(d * Aen[n]);
            h[n] = a * h[n] + du * Bt[n];
            y += h[n] * Ct[n];
        }
        float sz = zv[i] / (1.f + __expf(-zv[i]));
        float yv = (y + uu * De) * sz;
        unsigned short hh, ll;
        split2(yv, hh, ll);
        yh[(size_t)(t0 + i) * 1024 + e] = hh;
        yl[(size_t)(t0 + i) * 1024 + e] = ll;
    }
}

// ------------------------------- launcher -----------------------------------
extern "C" void kernel_launch(void* const* d_in, const int* in_sizes, int n_in,
                              void* d_out, int out_size, void* d_ws, size_t ws_size,
                              hipStream_t stream)
{
    const void* x    = d_in[0];
    const void* pos  = d_in[1];
    const void* nw   = d_in[2];
    const void* ipw  = d_in[3];   // (6,2048,512)
    const void* cw   = d_in[4];   // (6,1024,4)
    const void* cb   = d_in[5];   // (6,1024)
    const void* xpw  = d_in[6];   // (6,64,1024)
    const void* dtw  = d_in[7];   // (6,1024,32)
    const void* dtb  = d_in[8];   // (6,1024)
    const void* alog = d_in[9];   // (6,1024,16)
    const void* Dw   = d_in[10];  // (6,1024)
    const void* ow   = d_in[11];  // (6,512,1024)

    char* w = (char*)d_ws;
    auto take = [&](size_t bytes) { char* p = w; w += (bytes + 255) & ~255ull; return p; };

    float* h    = (float*)take(2048ull * 512 * 4);
    float* xz   = (float*)take(2048ull * 2048 * 4);
    float* xi   = (float*)take(2048ull * 1024 * 4);
    float* dtf  = (float*)take(2048ull * 1024 * 4);
    float* dbc  = (float*)take(2048ull * 64 * 4);
    float* P    = (float*)take(2ull * NCH * 16 * 1024 * 4);   // 8 MB (also H0)
    float* S    = (float*)take(2ull * NCH * 16 * 1024 * 4);   // 8 MB
    float* Pxp  = (float*)take(8ull * 2048 * 64 * 4);
    unsigned short* xnh = (unsigned short*)take(2048ull * 512 * 2);
    unsigned short* xnl = (unsigned short*)take(2048ull * 512 * 2);
    unsigned short* xih = (unsigned short*)take(2048ull * 1024 * 2);
    unsigned short* xil = (unsigned short*)take(2048ull * 1024 * 2);
    unsigned short* yh  = (unsigned short*)take(2048ull * 1024 * 2);
    unsigned short* yl  = (unsigned short*)take(2048ull * 1024 * 2);
    unsigned short* dth = (unsigned short*)take(2048ull * 32 * 2);
    unsigned short* dtl = (unsigned short*)take(2048ull * 32 * 2);
    unsigned short* wip_h = (unsigned short*)take(6ull * 2048 * 512 * 2);
    unsigned short* wip_l = (unsigned short*)take(6ull * 2048 * 512 * 2);
    unsigned short* wow_h = (unsigned short*)take(6ull * 512 * 1024 * 2);
    unsigned short* wow_l = (unsigned short*)take(6ull * 512 * 1024 * 2);
    unsigned short* wxp_h = (unsigned short*)take(6ull * 64 * 1024 * 2);
    unsigned short* wxp_l = (unsigned short*)take(6ull * 64 * 1024 * 2);
    unsigned short* wdt_h = (unsigned short*)take(6ull * 1024 * 32 * 2);
    unsigned short* wdt_l = (unsigned short*)take(6ull * 1024 * 32 * 2);
    int* flag = (int*)take(256);

    wsplit_all<<<(S1 + S2 + S3 + S4 + 255) / 256, 256, 0, stream>>>(
        ipw, ow, xpw, dtw, Dw,
        wip_h, wip_l, wow_h, wow_l, wxp_h, wxp_l, wdt_h, wdt_l, flag);

    for (int l = 0; l < 6; ++l) {
        // rmsnorm(h + pos): layer 0 reads x (dynamic dtype), else fp32 h
        rmsnorm_k<<<2048, 256, 0, stream>>>(
            l == 0 ? x : (const void*)h, l == 0 ? 1 : 0, pos, nw, flag, xnh, xnl);
        // in_proj: (T,512) x (2048,512)^T -> xz (T,2048), 128x128 tile
        gemm128<<<dim3(16, 16), 256, 0, stream>>>(
            xnh, xnl, 512, wip_h, wip_l, (long)l * 2048 * 512, xz, 2048, 512);
        conv_silu_k<<<8192, 256, 0, stream>>>(xz, cw, (long)l * 4096, cb, (long)l * 1024,
                                              flag, xi, xih, xil);
        // x_proj: (T,1024) x (64,1024)^T, split-K x8 -> Pxp, then reduce
        gemm_hl<0><<<dim3(32, 1, 8), 256, 0, stream>>>(
            xih, xil, 1024, wxp_h, wxp_l, (long)l * 64 * 1024,
            Pxp, 2048l * 64, nullptr, 0, flag, 64, 1024, 128);
        xp_reduce<<<512, 256, 0, stream>>>(Pxp, dbc, dth, dtl);
        // dt_proj: (T,32) x (1024,32)^T + dt_b, softplus -> dtf (T,1024)
        gemm_hl<1><<<dim3(32, 16), 256, 0, stream>>>(
            dth, dtl, 32, wdt_h, wdt_l, (long)l * 1024 * 32,
            dtf, 0, dtb, (long)l * 1024, flag, 1024, 32, 32);
        scan_stage1<<<512, 256, 0, stream>>>(dtf, xi, dbc, alog, (long)l * 16384,
                                             flag, P, S);
        scan_stage2<<<128, 256, 0, stream>>>(P, S);
        scan_stage3<<<512, 256, 0, stream>>>(dtf, xi, dbc, alog, (long)l * 16384,
                                             Dw, (long)l * 1024, flag, xz, P, yh, yl);
        // out_proj: (T,1024) x (512,1024)^T -> h (T,512); last layer -> d_out
        float* outp = (l < 5) ? h : (float*)d_out;
        gemm_hl<0><<<dim3(32, 8), 256, 0, stream>>>(
            yh, yl, 1024, wow_h, wow_l, (long)l * 512 * 1024,
            outp, 0, nullptr, 0, flag, 512, 1024, 1024);
    }
}

// Round 3
// 835.525 us; speedup vs baseline: 1.0352x; 1.0116x over previous
//
#include <hip/hip_runtime.h>
#include <hip/hip_bf16.h>

// ---------------------------------------------------------------------------
// Mamba encoder fwd: B=2, L=1024, D=512, E=1024, N=16, R=32, 6 layers.
// R2: fused xp_reduce + dt_proj(fp32 VALU) + scan_stage1 into one kernel;
// Dsum trick (store sum(dt) per chunk instead of 16 decay products; stage2
// recomputes decay with one exp). Chain: 10 -> 8 launches/layer.
// GEMMs keep R1's 2-phase register-staged pipeline.
// ---------------------------------------------------------------------------

typedef __attribute__((ext_vector_type(8))) short bf16x8;
typedef __attribute__((ext_vector_type(4))) float f32x4;

__device__ __forceinline__ float bf2f(unsigned short u) {
    unsigned int x = ((unsigned int)u) << 16;
    return __builtin_bit_cast(float, x);
}
__device__ __forceinline__ unsigned short f2bf(float f) {
    __hip_bfloat16 h = __float2bfloat16(f);   // RNE
    return __builtin_bit_cast(unsigned short, h);
}
__device__ __forceinline__ float ldin(const void* p, size_t i, int isbf) {
    return isbf ? bf2f(((const unsigned short*)p)[i]) : ((const float*)p)[i];
}
__device__ __forceinline__ float softplus_f(float x) {
    return (x > 20.f) ? x : log1pf(__expf(x));
}
__device__ __forceinline__ void split2(float x, unsigned short& h, unsigned short& l) {
    h = f2bf(x);
    l = f2bf(x - bf2f(h));   // == 0 when x is exactly bf16
}

// --------- all-weights pre-split (+ dtype flag publish), one kernel ---------
// dt_proj weights no longer split (dt GEMM is fp32 VALU now).
#define S1 (6*2048*512)
#define S2 (6*512*1024)
#define S3 (6*64*1024)
__global__ __launch_bounds__(256) void wsplit_all(
    const void* __restrict__ ipw, const void* __restrict__ ow,
    const void* __restrict__ xpw, const void* __restrict__ Dw,
    unsigned short* __restrict__ h1, unsigned short* __restrict__ l1,
    unsigned short* __restrict__ h2, unsigned short* __restrict__ l2,
    unsigned short* __restrict__ h3, unsigned short* __restrict__ l3,
    int* __restrict__ flag)
{
    int g = blockIdx.x * 256 + threadIdx.x;
    const int isbf = (*(const unsigned int*)Dw == 0x3F800000u) ? 0 : 1;
    if (g == 0) *flag = isbf;
    const void* src; unsigned short *dh, *dl; int i;
    if (g < S1)                { src = ipw; dh = h1; dl = l1; i = g; }
    else if (g < S1+S2)        { src = ow;  dh = h2; dl = l2; i = g - S1; }
    else if (g < S1+S2+S3)     { src = xpw; dh = h3; dl = l3; i = g - S1 - S2; }
    else return;
    unsigned short hh, ll;
    split2(ldin(src, i, isbf), hh, ll);
    dh[i] = hh; dl[i] = ll;
}

// ------------------ GEMM 128x128 tile (in_proj): C = A * W^T ----------------
__global__ __launch_bounds__(256) void gemm128(
    const unsigned short* __restrict__ Ah, const unsigned short* __restrict__ Al,
    int lda,
    const unsigned short* __restrict__ Wh, const unsigned short* __restrict__ Wl,
    long woff,
    float* __restrict__ Cf, int N, int K)
{
    __shared__ __align__(16) unsigned short As[2][128][40];
    __shared__ __align__(16) unsigned short Ws[2][128][40];

    const int m0 = blockIdx.x * 128, n0 = blockIdx.y * 128;
    const int t = threadIdx.x, lane = t & 63, wave = t >> 6;
    const int wm = (wave & 1) * 64, wn = (wave >> 1) * 64;
    const int srow = t >> 1, scol = (t & 1) * 16;

    const unsigned short* ah = Ah + (size_t)(m0 + srow) * lda + scol;
    const unsigned short* al = Al + (size_t)(m0 + srow) * lda + scol;
    const unsigned short* wh = Wh + woff + (size_t)(n0 + srow) * K + scol;
    const unsigned short* wl = Wl + woff + (size_t)(n0 + srow) * K + scol;

    f32x4 acc[4][4] = {};
    const int fm = lane & 15, fk = (lane >> 4) * 8;

    uint4 r0, r1, r2, r3, r4, r5, r6, r7;
#define LD128(K0) do { \
        r0 = *(const uint4*)(ah + (K0));     r1 = *(const uint4*)(ah + (K0) + 8); \
        r2 = *(const uint4*)(al + (K0));     r3 = *(const uint4*)(al + (K0) + 8); \
        r4 = *(const uint4*)(wh + (K0));     r5 = *(const uint4*)(wh + (K0) + 8); \
        r6 = *(const uint4*)(wl + (K0));     r7 = *(const uint4*)(wl + (K0) + 8); \
    } while (0)
#define ST128() do { \
        *(uint4*)(&As[0][srow][scol])     = r0; *(uint4*)(&As[0][srow][scol + 8]) = r1; \
        *(uint4*)(&As[1][srow][scol])     = r2; *(uint4*)(&As[1][srow][scol + 8]) = r3; \
        *(uint4*)(&Ws[0][srow][scol])     = r4; *(uint4*)(&Ws[0][srow][scol + 8]) = r5; \
        *(uint4*)(&Ws[1][srow][scol])     = r6; *(uint4*)(&Ws[1][srow][scol + 8]) = r7; \
    } while (0)

    LD128(0);
    ST128();
    __syncthreads();

    for (int k0 = 0; k0 < K; k0 += 32) {
        const int more = (k0 + 32 < K);
        if (more) LD128(k0 + 32);            // issue next tile early

        bf16x8 a_h[4], a_l[4], w_h[4], w_l[4];
#pragma unroll
        for (int i = 0; i < 4; ++i) {
            a_h[i] = *(const bf16x8*)(&As[0][wm + i * 16 + fm][fk]);
            a_l[i] = *(const bf16x8*)(&As[1][wm + i * 16 + fm][fk]);
            w_h[i] = *(const bf16x8*)(&Ws[0][wn + i * 16 + fm][fk]);
            w_l[i] = *(const bf16x8*)(&Ws[1][wn + i * 16 + fm][fk]);
        }
#pragma unroll
        for (int mi = 0; mi < 4; ++mi)
#pragma unroll
            for (int ni = 0; ni < 4; ++ni) {
                acc[mi][ni] = __builtin_amdgcn_mfma_f32_16x16x32_bf16(
                    a_h[mi], w_h[ni], acc[mi][ni], 0, 0, 0);
                acc[mi][ni] = __builtin_amdgcn_mfma_f32_16x16x32_bf16(
                    a_h[mi], w_l[ni], acc[mi][ni], 0, 0, 0);
                acc[mi][ni] = __builtin_amdgcn_mfma_f32_16x16x32_bf16(
                    a_l[mi], w_h[ni], acc[mi][ni], 0, 0, 0);
            }

        if (more) {
            __syncthreads();
            ST128();
            __syncthreads();
        }
    }
#undef LD128
#undef ST128

    const int col = lane & 15, rb = (lane >> 4) * 4;
#pragma unroll
    for (int mi = 0; mi < 4; ++mi)
#pragma unroll
        for (int ni = 0; ni < 4; ++ni)
#pragma unroll
            for (int r = 0; r < 4; ++r) {
                int gm = m0 + wm + mi * 16 + rb + r;
                int gn = n0 + wn + ni * 16 + col;
                Cf[(size_t)gm * N + gn] = acc[mi][ni][r];
            }
}

// ----------------------- GEMM 64x64 tile: C = A * W^T -----------------------
template <int ACT>
__global__ __launch_bounds__(256) void gemm_hl(
    const unsigned short* __restrict__ Ah, const unsigned short* __restrict__ Al,
    int lda,
    const unsigned short* __restrict__ Wh, const unsigned short* __restrict__ Wl,
    long woff,
    float* __restrict__ Cf, long zstride,
    const void* __restrict__ bias, long boff, const int* __restrict__ flag,
    int N, int K, int Kc)
{
    const int isbf = *flag;
    __shared__ __align__(16) unsigned short As[2][64][40];
    __shared__ __align__(16) unsigned short Ws[2][64][40];

    const int m0 = blockIdx.x * 64, n0 = blockIdx.y * 64;
    const int kb = blockIdx.z * Kc;
    const int t = threadIdx.x;
    const int lane = t & 63, wave = t >> 6;
    const int wm = (wave & 1) * 32, wn = (wave >> 1) * 32;
    const int srow = t >> 2, scol = (t & 3) * 8;

    const unsigned short* ah = Ah + (size_t)(m0 + srow) * lda + scol;
    const unsigned short* al = Al + (size_t)(m0 + srow) * lda + scol;
    const unsigned short* wh = Wh + woff + (size_t)(n0 + srow) * K + scol;
    const unsigned short* wl = Wl + woff + (size_t)(n0 + srow) * K + scol;

    f32x4 acc[2][2] = {};

    uint4 r0, r1, r2, r3;
#define LD64(K0) do { \
        r0 = *(const uint4*)(ah + (K0)); \
        r1 = *(const uint4*)(al + (K0)); \
        r2 = *(const uint4*)(wh + (K0)); \
        r3 = *(const uint4*)(wl + (K0)); \
    } while (0)
#define ST64() do { \
        *(uint4*)(&As[0][srow][scol]) = r0; \
        *(uint4*)(&As[1][srow][scol]) = r1; \
        *(uint4*)(&Ws[0][srow][scol]) = r2; \
        *(uint4*)(&Ws[1][srow][scol]) = r3; \
    } while (0)

    LD64(kb);
    ST64();
    __syncthreads();

    for (int k0 = kb; k0 < kb + Kc; k0 += 32) {
        const int more = (k0 + 32 < kb + Kc);
        if (more) LD64(k0 + 32);

        const int fm = lane & 15, fk = (lane >> 4) * 8;
        bf16x8 a0h = *(const bf16x8*)(&As[0][wm + fm][fk]);
        bf16x8 a1h = *(const bf16x8*)(&As[0][wm + 16 + fm][fk]);
        bf16x8 w0h = *(const bf16x8*)(&Ws[0][wn + fm][fk]);
        bf16x8 w1h = *(const bf16x8*)(&Ws[0][wn + 16 + fm][fk]);
        bf16x8 a0l = *(const bf16x8*)(&As[1][wm + fm][fk]);
        bf16x8 a1l = *(const bf16x8*)(&As[1][wm + 16 + fm][fk]);
        bf16x8 w0l = *(const bf16x8*)(&Ws[1][wn + fm][fk]);
        bf16x8 w1l = *(const bf16x8*)(&Ws[1][wn + 16 + fm][fk]);

        acc[0][0] = __builtin_amdgcn_mfma_f32_16x16x32_bf16(a0h, w0h, acc[0][0], 0, 0, 0);
        acc[0][1] = __builtin_amdgcn_mfma_f32_16x16x32_bf16(a0h, w1h, acc[0][1], 0, 0, 0);
        acc[1][0] = __builtin_amdgcn_mfma_f32_16x16x32_bf16(a1h, w0h, acc[1][0], 0, 0, 0);
        acc[1][1] = __builtin_amdgcn_mfma_f32_16x16x32_bf16(a1h, w1h, acc[1][1], 0, 0, 0);
        acc[0][0] = __builtin_amdgcn_mfma_f32_16x16x32_bf16(a0h, w0l, acc[0][0], 0, 0, 0);
        acc[0][1] = __builtin_amdgcn_mfma_f32_16x16x32_bf16(a0h, w1l, acc[0][1], 0, 0, 0);
        acc[1][0] = __builtin_amdgcn_mfma_f32_16x16x32_bf16(a1h, w0l, acc[1][0], 0, 0, 0);
        acc[1][1] = __builtin_amdgcn_mfma_f32_16x16x32_bf16(a1h, w1l, acc[1][1], 0, 0, 0);
        acc[0][0] = __builtin_amdgcn_mfma_f32_16x16x32_bf16(a0l, w0h, acc[0][0], 0, 0, 0);
        acc[0][1] = __builtin_amdgcn_mfma_f32_16x16x32_bf16(a0l, w1h, acc[0][1], 0, 0, 0);
        acc[1][0] = __builtin_amdgcn_mfma_f32_16x16x32_bf16(a1l, w0h, acc[1][0], 0, 0, 0);
        acc[1][1] = __builtin_amdgcn_mfma_f32_16x16x32_bf16(a1l, w1h, acc[1][1], 0, 0, 0);

        if (more) {
            __syncthreads();
            ST64();
            __syncthreads();
        }
    }
#undef LD64
#undef ST64

    float* Cp = Cf + (size_t)blockIdx.z * zstride;
    const int col = lane & 15, rb = (lane >> 4) * 4;
#pragma unroll
    for (int mi = 0; mi < 2; ++mi)
#pragma unroll
        for (int ni = 0; ni < 2; ++ni)
#pragma unroll
            for (int r = 0; r < 4; ++r) {
                int gm = m0 + wm + mi * 16 + rb + r;
                int gn = n0 + wn + ni * 16 + col;
                float v = acc[mi][ni][r];
                if (bias) v += ldin(bias, boff + gn, isbf);
                if (ACT == 1) v = softplus_f(v);
                Cp[(size_t)gm * N + gn] = v;
            }
}

// ------------------- RMSNorm(h + pos) -> pre-split bf16 ---------------------
__global__ __launch_bounds__(256) void rmsnorm_k(
    const void* __restrict__ hsrc, int hdyn, const void* __restrict__ pos,
    const void* __restrict__ nw, const int* __restrict__ flag,
    unsigned short* __restrict__ xnh, unsigned short* __restrict__ xnl)
{
    const int isbf = *flag;
    const int row = blockIdx.x;
    const int t = threadIdx.x;
    const size_t base = (size_t)row * 512;
    float h0 = hdyn ? ldin(hsrc, base + t, isbf)       : ((const float*)hsrc)[base + t];
    float h1 = hdyn ? ldin(hsrc, base + 256 + t, isbf) : ((const float*)hsrc)[base + 256 + t];
    float v0 = h0 + ldin(pos, base + t, isbf);
    float v1 = h1 + ldin(pos, base + 256 + t, isbf);
    float ss = v0 * v0 + v1 * v1;
#pragma unroll
    for (int o = 32; o; o >>= 1) ss += __shfl_xor(ss, o, 64);
    __shared__ float sw[4];
    if ((t & 63) == 0) sw[t >> 6] = ss;
    __syncthreads();
    float tot = sw[0] + sw[1] + sw[2] + sw[3];
    float sc = rsqrtf(tot * (1.0f / 512.0f) + 1.1920929e-07f);
    float o0 = v0 * sc * ldin(nw, t, isbf);
    float o1 = v1 * sc * ldin(nw, 256 + t, isbf);
    unsigned short hh, ll;
    split2(o0, hh, ll); xnh[base + t] = hh;       xnl[base + t] = ll;
    split2(o1, hh, ll); xnh[base + 256 + t] = hh; xnl[base + 256 + t] = ll;
}

// ------- causal depthwise conv (k=4) + SiLU -> fp32 u + pre-split bf16 ------
__global__ __launch_bounds__(256) void conv_silu_k(
    const float* __restrict__ xz,
    const void* __restrict__ cw, long cwoff,
    const void* __restrict__ cb, long cboff,
    const int* __restrict__ flag,
    float* __restrict__ xi,
    unsigned short* __restrict__ xih, unsigned short* __restrict__ xil)
{
    const int isbf = *flag;
    int g = blockIdx.x * 256 + threadIdx.x;   // T*E = 2M
    int e = g & 1023;
    int l = (g >> 10) & 1023;
    int b = g >> 20;
    float acc = ldin(cb, cboff + e, isbf);
#pragma unroll
    for (int k = 0; k < 4; ++k) {
        int ls = l - 3 + k;
        if (ls >= 0)
            acc += ldin(cw, cwoff + e * 4 + k, isbf) *
                   xz[((size_t)(b * 1024 + ls)) * 2048 + e];
    }
    acc = acc / (1.f + __expf(-acc));         // SiLU
    xi[g] = acc;
    unsigned short hh, ll;
    split2(acc, hh, ll);
    xih[g] = hh; xil[g] = ll;
}

// --------------------- selective scan, chunked (64 x 16) --------------------
#define CL 16
#define NCH 64

// Fused: split-K reduce of x_proj partials -> dbc; dt_proj (fp32 VALU dot,
// K=32) + bias + softplus -> dtf; chunk-local scan -> S + Dsum.
// Grid: (c=64, eg=4, b=2) x 256 threads. e = eg*256 + tid.
__global__ __launch_bounds__(256) void xp_dt_scan1(
    const float* __restrict__ Pxp,
    const void* __restrict__ dtw, long dtwoff,
    const void* __restrict__ dtb, long dtboff,
    const void* __restrict__ alog, long aoff,
    const float* __restrict__ xi,
    const int* __restrict__ flag,
    float* __restrict__ dbc, float* __restrict__ dtf,
    float* __restrict__ S, float* __restrict__ Dsum)
{
    const int isbf = *flag;
    const int tid = threadIdx.x;
    const int c = blockIdx.x, eg = blockIdx.y, b = blockIdx.z;
    const int t0 = b * 1024 + c * CL;

    __shared__ float red[CL][64];             // reduced dbc rows for this chunk

    // Phase A: reduce Pxp (8 z-slices) for 16 rows x 64 cols.
    for (int idx = tid; idx < CL * 64; idx += 256) {
        int ti = idx >> 6, n = idx & 63;
        float s = 0.f;
#pragma unroll
        for (int z = 0; z < 8; ++z)
            s += Pxp[(size_t)z * 131072 + (size_t)(t0 + ti) * 64 + n];
        red[ti][n] = s;
        if (eg == 0) dbc[(size_t)(t0 + ti) * 64 + n] = s;
    }
    __syncthreads();

    const int e = eg * 256 + tid;

    // Phase B: dt = softplus(dot32(red[i][0:32], dtw[e]) + dtb[e]), fp32.
    float wrow[32];
#pragma unroll
    for (int k = 0; k < 32; ++k) wrow[k] = ldin(dtw, dtwoff + (size_t)e * 32 + k, isbf);
    const float bias = ldin(dtb, dtboff + e, isbf);

    float dv[CL];
#pragma unroll
    for (int i = 0; i < CL; ++i) {
        const float4* rp = (const float4*)&red[i][0];
        float acc = bias;
#pragma unroll
        for (int k4 = 0; k4 < 8; ++k4) {
            float4 r4 = rp[k4];
            acc += r4.x * wrow[k4 * 4 + 0] + r4.y * wrow[k4 * 4 + 1]
                 + r4.z * wrow[k4 * 4 + 2] + r4.w * wrow[k4 * 4 + 3];
        }
        dv[i] = softplus_f(acc);
        dtf[(size_t)(t0 + i) * 1024 + e] = dv[i];
    }

    // Phase C: chunk scan (16 steps, 16 states), S + Dsum out.
    float Aen[16], Sn[16];
#pragma unroll
    for (int n = 0; n < 16; ++n) {
        Aen[n] = -__expf(ldin(alog, aoff + (size_t)e * 16 + n, isbf));
        Sn[n] = 0.f;
    }
    float ds = 0.f;
#pragma unroll
    for (int i = 0; i < CL; ++i) {
        float d = dv[i];
        ds += d;
        float du = d * xi[(size_t)(t0 + i) * 1024 + e];
        const float4* Bp = (const float4*)&red[i][32];
        float4 b0 = Bp[0], b1 = Bp[1], b2 = Bp[2], b3 = Bp[3];
        float Bt[16] = {b0.x,b0.y,b0.z,b0.w, b1.x,b1.y,b1.z,b1.w,
                        b2.x,b2.y,b2.z,b2.w, b3.x,b3.y,b3.z,b3.w};
#pragma unroll
        for (int n = 0; n < 16; ++n) {
            float a = __expf(d * Aen[n]);
            Sn[n] = a * Sn[n] + du * Bt[n];
        }
    }
    size_t ob = ((size_t)(b * NCH + c) * 16) * 1024 + e;
#pragma unroll
    for (int n = 0; n < 16; ++n) S[ob + (size_t)n * 1024] = Sn[n];
    Dsum[(size_t)(b * NCH + c) * 1024 + e] = ds;
}

// cross-chunk combine: decay recomputed from Dsum (one exp per step).
__global__ __launch_bounds__(256) void scan_stage2(
    const float* __restrict__ S, const float* __restrict__ Dsum,
    const void* __restrict__ alog, long aoff, const int* __restrict__ flag,
    float* __restrict__ H0)
{
    const int isbf = *flag;
    int g = blockIdx.x * 256 + threadIdx.x;   // 32768: e + 1024n + 16384b
    int e = g & 1023, n = (g >> 10) & 15, b = g >> 14;
    const float Aen = -__expf(ldin(alog, aoff + (size_t)e * 16 + n, isbf));
    float H = 0.f;
    for (int cb = 0; cb < NCH; cb += 8) {
        float s[8], pj[8];
#pragma unroll
        for (int j = 0; j < 8; ++j) {
            size_t idx = ((size_t)(b * NCH + cb + j) * 16 + n) * 1024 + e;
            s[j] = S[idx];
            pj[j] = __expf(Dsum[(size_t)(b * NCH + cb + j) * 1024 + e] * Aen);
        }
#pragma unroll
        for (int j = 0; j < 8; ++j) {
            size_t idx = ((size_t)(b * NCH + cb + j) * 16 + n) * 1024 + e;
            H0[idx] = H;
            H = pj[j] * H + s[j];
        }
    }
}

// final sweep: y = sum_n C*h + u*D, gate with silu(z); emit pre-split bf16.
__global__ __launch_bounds__(256) void scan_stage3(
    const float* __restrict__ dtp, const float* __restrict__ u,
    const float* __restrict__ dbc,
    const void* __restrict__ alog, long aoff,
    const void* __restrict__ Dv, long doff,
    const int* __restrict__ flag,
    const float* __restrict__ xz, const float* __restrict__ H0,
    unsigned short* __restrict__ yh, unsigned short* __restrict__ yl)
{
    const int isbf = *flag;
    int g = blockIdx.x * 256 + threadIdx.x;   // 131072
    int e = g & 1023, c = (g >> 10) & (NCH - 1), b = g >> 16;
    int t0 = b * 1024 + c * CL;

    float dv[CL], uv[CL], zv[CL];
#pragma unroll
    for (int i = 0; i < CL; ++i) {
        dv[i] = dtp[(size_t)(t0 + i) * 1024 + e];
        uv[i] = u[(size_t)(t0 + i) * 1024 + e];
        zv[i] = xz[(size_t)(t0 + i) * 2048 + 1024 + e];
    }

    float Aen[16], h[16];
    size_t ob = ((size_t)(b * NCH + c) * 16) * 1024 + e;
#pragma unroll
    for (int n = 0; n < 16; ++n) {
        Aen[n] = -__expf(ldin(alog, aoff + (size_t)e * 16 + n, isbf));
        h[n] = H0[ob + (size_t)n * 1024];
    }
    float De = ldin(Dv, doff + e, isbf);
#pragma unroll
    for (int i = 0; i < CL; ++i) {
        float d = dv[i], uu = uv[i], du = d * uu;
        const float4* Bp = (const float4*)(dbc + (size_t)(t0 + i) * 64 + 32);
        float4 b0 = Bp[0], b1 = Bp[1], b2 = Bp[2], b3 = Bp[3];
        float4 c0 = Bp[4], c1 = Bp[5], c2 = Bp[6], c3 = Bp[7];
        float Bt[16] = {b0.x,b0.y,b0.z,b0.w, b1.x,b1.y,b1.z,b1.w,
                        b2.x,b2.y,b2.z,b2.w, b3.x,b3.y,b3.z,b3.w};
        float Ct[16] = {c0.x,c0.y,c0.z,c0.w, c1.x,c1.y,c1.z,c1.w,
                        c2.x,c2.y,c2.z,c2.w, c3.x,c3.y,c3.z,c3.w};
        float y = 0.f;
#pragma unroll
        for (int n = 0; n < 16; ++n) {
            float a = __expf(d * Aen[n]);
            h[n] = a * h[n] + du * Bt[n];
            y += h[n] * Ct[n];
        }
        float sz = zv[i] / (1.f + __expf(-zv[i]));
        float yv = (y + uu * De) * sz;
        unsigned short hh, ll;
        split2(yv, hh, ll);
        yh[(size_t)(t0 + i) * 1024 + e] = hh;
        yl[(size_t)(t0 + i) * 1024 + e] = ll;
    }
}

// ------------------------------- launcher -----------------------------------
extern "C" void kernel_launch(void* const* d_in, const int* in_sizes, int n_in,
                              void* d_out, int out_size, void* d_ws, size_t ws_size,
                              hipStream_t stream)
{
    const void* x    = d_in[0];
    const void* pos  = d_in[1];
    const void* nw   = d_in[2];
    const void* ipw  = d_in[3];   // (6,2048,512)
    const void* cw   = d_in[4];   // (6,1024,4)
    const void* cb   = d_in[5];   // (6,1024)
    const void* xpw  = d_in[6];   // (6,64,1024)
    const void* dtw  = d_in[7];   // (6,1024,32)
    const void* dtb  = d_in[8];   // (6,1024)
    const void* alog = d_in[9];   // (6,1024,16)
    const void* Dw   = d_in[10];  // (6,1024)
    const void* ow   = d_in[11];  // (6,512,1024)

    char* w = (char*)d_ws;
    auto take = [&](size_t bytes) { char* p = w; w += (bytes + 255) & ~255ull; return p; };

    float* h    = (float*)take(2048ull * 512 * 4);
    float* xz   = (float*)take(2048ull * 2048 * 4);
    float* xi   = (float*)take(2048ull * 1024 * 4);
    float* dtf  = (float*)take(2048ull * 1024 * 4);
    float* dbc  = (float*)take(2048ull * 64 * 4);
    float* S    = (float*)take(2ull * NCH * 16 * 1024 * 4);   // 8 MB
    float* H0   = (float*)take(2ull * NCH * 16 * 1024 * 4);   // 8 MB
    float* Dsum = (float*)take(2ull * NCH * 1024 * 4);        // 0.5 MB
    float* Pxp  = (float*)take(8ull * 2048 * 64 * 4);
    unsigned short* xnh = (unsigned short*)take(2048ull * 512 * 2);
    unsigned short* xnl = (unsigned short*)take(2048ull * 512 * 2);
    unsigned short* xih = (unsigned short*)take(2048ull * 1024 * 2);
    unsigned short* xil = (unsigned short*)take(2048ull * 1024 * 2);
    unsigned short* yh  = (unsigned short*)take(2048ull * 1024 * 2);
    unsigned short* yl  = (unsigned short*)take(2048ull * 1024 * 2);
    unsigned short* wip_h = (unsigned short*)take(6ull * 2048 * 512 * 2);
    unsigned short* wip_l = (unsigned short*)take(6ull * 2048 * 512 * 2);
    unsigned short* wow_h = (unsigned short*)take(6ull * 512 * 1024 * 2);
    unsigned short* wow_l = (unsigned short*)take(6ull * 512 * 1024 * 2);
    unsigned short* wxp_h = (unsigned short*)take(6ull * 64 * 1024 * 2);
    unsigned short* wxp_l = (unsigned short*)take(6ull * 64 * 1024 * 2);
    int* flag = (int*)take(256);

    wsplit_all<<<(S1 + S2 + S3 + 255) / 256, 256, 0, stream>>>(
        ipw, ow, xpw, Dw,
        wip_h, wip_l, wow_h, wow_l, wxp_h, wxp_l, flag);

    for (int l = 0; l < 6; ++l) {
        // rmsnorm(h + pos): layer 0 reads x (dynamic dtype), else fp32 h
        rmsnorm_k<<<2048, 256, 0, stream>>>(
            l == 0 ? x : (const void*)h, l == 0 ? 1 : 0, pos, nw, flag, xnh, xnl);
        // in_proj: (T,512) x (2048,512)^T -> xz (T,2048), 128x128 tile
        gemm128<<<dim3(16, 16), 256, 0, stream>>>(
            xnh, xnl, 512, wip_h, wip_l, (long)l * 2048 * 512, xz, 2048, 512);
        conv_silu_k<<<8192, 256, 0, stream>>>(xz, cw, (long)l * 4096, cb, (long)l * 1024,
                                              flag, xi, xih, xil);
        // x_proj: (T,1024) x (64,1024)^T, split-K x8 -> Pxp
        gemm_hl<0><<<dim3(32, 1, 8), 256, 0, stream>>>(
            xih, xil, 1024, wxp_h, wxp_l, (long)l * 64 * 1024,
            Pxp, 2048l * 64, nullptr, 0, flag, 64, 1024, 128);
        // fused: reduce + dt_proj(fp32) + chunk scan -> dbc, dtf, S, Dsum
        xp_dt_scan1<<<dim3(NCH, 4, 2), 256, 0, stream>>>(
            Pxp, dtw, (long)l * 1024 * 32, dtb, (long)l * 1024,
            alog, (long)l * 16384, xi, flag, dbc, dtf, S, Dsum);
        scan_stage2<<<128, 256, 0, stream>>>(S, Dsum, alog, (long)l * 16384, flag, H0);
        scan_stage3<<<512, 256, 0, stream>>>(dtf, xi, dbc, alog, (long)l * 16384,
                                             Dw, (long)l * 1024, flag, xz, H0, yh, yl);
        // out_proj: (T,1024) x (512,1024)^T -> h (T,512); last layer -> d_out
        float* outp = (l < 5) ? h : (float*)d_out;
        gemm_hl<0><<<dim3(32, 8), 256, 0, stream>>>(
            yh, yl, 1024, wow_h, wow_l, (long)l * 512 * 1024,
            outp, 0, nullptr, 0, flag, 512, 1024, 1024);
    }
}

// Round 4
// 819.553 us; speedup vs baseline: 1.0553x; 1.0195x over previous
//
#include <hip/hip_runtime.h>
#include <hip/hip_bf16.h>

// ---------------------------------------------------------------------------
// Mamba encoder fwd: B=2, L=1024, D=512, E=1024, N=16, R=32, 6 layers.
// R3: fix xp_dt_scan1 register-residency (was VGPR=40 -> rematerialized
// loads, 77us). launch_bounds(256,1); dt weights pre-transposed k-major fp32
// (coalesced); Aen = -exp(A_log) precomputed n-major fp32 (coalesced, no exp
// in scan kernels); u batch-preloaded. Same fixes on stage2/3.
// ---------------------------------------------------------------------------

typedef __attribute__((ext_vector_type(8))) short bf16x8;
typedef __attribute__((ext_vector_type(4))) float f32x4;

__device__ __forceinline__ float bf2f(unsigned short u) {
    unsigned int x = ((unsigned int)u) << 16;
    return __builtin_bit_cast(float, x);
}
__device__ __forceinline__ unsigned short f2bf(float f) {
    __hip_bfloat16 h = __float2bfloat16(f);   // RNE
    return __builtin_bit_cast(unsigned short, h);
}
__device__ __forceinline__ float ldin(const void* p, size_t i, int isbf) {
    return isbf ? bf2f(((const unsigned short*)p)[i]) : ((const float*)p)[i];
}
__device__ __forceinline__ float softplus_f(float x) {
    return (x > 20.f) ? x : log1pf(__expf(x));
}
__device__ __forceinline__ void split2(float x, unsigned short& h, unsigned short& l) {
    h = f2bf(x);
    l = f2bf(x - bf2f(h));   // == 0 when x is exactly bf16
}

// --------- all-weights prep (+ dtype flag publish), one kernel --------------
// split-bf16 for the 3 MFMA GEMMs; fp32 transposed dtwT (k-major) and
// AenT = -exp(A_log) (n-major) for the scan kernels.
#define S1 (6*2048*512)
#define S2 (6*512*1024)
#define S3 (6*64*1024)
#define S4 (6*1024*32)
#define S5 (6*1024*16)
__global__ __launch_bounds__(256) void wsplit_all(
    const void* __restrict__ ipw, const void* __restrict__ ow,
    const void* __restrict__ xpw, const void* __restrict__ dtw,
    const void* __restrict__ alog, const void* __restrict__ Dw,
    unsigned short* __restrict__ h1, unsigned short* __restrict__ l1,
    unsigned short* __restrict__ h2, unsigned short* __restrict__ l2,
    unsigned short* __restrict__ h3, unsigned short* __restrict__ l3,
    float* __restrict__ dtwT, float* __restrict__ AenT,
    int* __restrict__ flag)
{
    int g = blockIdx.x * 256 + threadIdx.x;
    const int isbf = (*(const unsigned int*)Dw == 0x3F800000u) ? 0 : 1;
    if (g == 0) *flag = isbf;
    if (g < S1 + S2 + S3) {
        const void* src; unsigned short *dh, *dl; int i;
        if (g < S1)            { src = ipw; dh = h1; dl = l1; i = g; }
        else if (g < S1 + S2)  { src = ow;  dh = h2; dl = l2; i = g - S1; }
        else                   { src = xpw; dh = h3; dl = l3; i = g - S1 - S2; }
        unsigned short hh, ll;
        split2(ldin(src, i, isbf), hh, ll);
        dh[i] = hh; dl[i] = ll;
    } else if (g < S1 + S2 + S3 + S4) {
        int i = g - (S1 + S2 + S3);              // (l, e, k) -> (l, k, e)
        int l = i >> 15, rem = i & 32767;
        int e = rem >> 5, k = rem & 31;
        dtwT[(size_t)l * 32768 + k * 1024 + e] =
            ldin(dtw, (size_t)l * 32768 + e * 32 + k, isbf);
    } else if (g < S1 + S2 + S3 + S4 + S5) {
        int i = g - (S1 + S2 + S3 + S4);         // (l, e, n) -> (l, n, e)
        int l = i >> 14, rem = i & 16383;
        int n = rem >> 10, e = rem & 1023;
        AenT[(size_t)l * 16384 + n * 1024 + e] =
            -__expf(ldin(alog, (size_t)l * 16384 + e * 16 + n, isbf));
    }
}

// ------------------ GEMM 128x128 tile (in_proj): C = A * W^T ----------------
__global__ __launch_bounds__(256) void gemm128(
    const unsigned short* __restrict__ Ah, const unsigned short* __restrict__ Al,
    int lda,
    const unsigned short* __restrict__ Wh, const unsigned short* __restrict__ Wl,
    long woff,
    float* __restrict__ Cf, int N, int K)
{
    __shared__ __align__(16) unsigned short As[2][128][40];
    __shared__ __align__(16) unsigned short Ws[2][128][40];

    const int m0 = blockIdx.x * 128, n0 = blockIdx.y * 128;
    const int t = threadIdx.x, lane = t & 63, wave = t >> 6;
    const int wm = (wave & 1) * 64, wn = (wave >> 1) * 64;
    const int srow = t >> 1, scol = (t & 1) * 16;

    const unsigned short* ah = Ah + (size_t)(m0 + srow) * lda + scol;
    const unsigned short* al = Al + (size_t)(m0 + srow) * lda + scol;
    const unsigned short* wh = Wh + woff + (size_t)(n0 + srow) * K + scol;
    const unsigned short* wl = Wl + woff + (size_t)(n0 + srow) * K + scol;

    f32x4 acc[4][4] = {};
    const int fm = lane & 15, fk = (lane >> 4) * 8;

    uint4 r0, r1, r2, r3, r4, r5, r6, r7;
#define LD128(K0) do { \
        r0 = *(const uint4*)(ah + (K0));     r1 = *(const uint4*)(ah + (K0) + 8); \
        r2 = *(const uint4*)(al + (K0));     r3 = *(const uint4*)(al + (K0) + 8); \
        r4 = *(const uint4*)(wh + (K0));     r5 = *(const uint4*)(wh + (K0) + 8); \
        r6 = *(const uint4*)(wl + (K0));     r7 = *(const uint4*)(wl + (K0) + 8); \
    } while (0)
#define ST128() do { \
        *(uint4*)(&As[0][srow][scol])     = r0; *(uint4*)(&As[0][srow][scol + 8]) = r1; \
        *(uint4*)(&As[1][srow][scol])     = r2; *(uint4*)(&As[1][srow][scol + 8]) = r3; \
        *(uint4*)(&Ws[0][srow][scol])     = r4; *(uint4*)(&Ws[0][srow][scol + 8]) = r5; \
        *(uint4*)(&Ws[1][srow][scol])     = r6; *(uint4*)(&Ws[1][srow][scol + 8]) = r7; \
    } while (0)

    LD128(0);
    ST128();
    __syncthreads();

    for (int k0 = 0; k0 < K; k0 += 32) {
        const int more = (k0 + 32 < K);
        if (more) LD128(k0 + 32);            // issue next tile early

        bf16x8 a_h[4], a_l[4], w_h[4], w_l[4];
#pragma unroll
        for (int i = 0; i < 4; ++i) {
            a_h[i] = *(const bf16x8*)(&As[0][wm + i * 16 + fm][fk]);
            a_l[i] = *(const bf16x8*)(&As[1][wm + i * 16 + fm][fk]);
            w_h[i] = *(const bf16x8*)(&Ws[0][wn + i * 16 + fm][fk]);
            w_l[i] = *(const bf16x8*)(&Ws[1][wn + i * 16 + fm][fk]);
        }
#pragma unroll
        for (int mi = 0; mi < 4; ++mi)
#pragma unroll
            for (int ni = 0; ni < 4; ++ni) {
                acc[mi][ni] = __builtin_amdgcn_mfma_f32_16x16x32_bf16(
                    a_h[mi], w_h[ni], acc[mi][ni], 0, 0, 0);
                acc[mi][ni] = __builtin_amdgcn_mfma_f32_16x16x32_bf16(
                    a_h[mi], w_l[ni], acc[mi][ni], 0, 0, 0);
                acc[mi][ni] = __builtin_amdgcn_mfma_f32_16x16x32_bf16(
                    a_l[mi], w_h[ni], acc[mi][ni], 0, 0, 0);
            }

        if (more) {
            __syncthreads();
            ST128();
            __syncthreads();
        }
    }
#undef LD128
#undef ST128

    const int col = lane & 15, rb = (lane >> 4) * 4;
#pragma unroll
    for (int mi = 0; mi < 4; ++mi)
#pragma unroll
        for (int ni = 0; ni < 4; ++ni)
#pragma unroll
            for (int r = 0; r < 4; ++r) {
                int gm = m0 + wm + mi * 16 + rb + r;
                int gn = n0 + wn + ni * 16 + col;
                Cf[(size_t)gm * N + gn] = acc[mi][ni][r];
            }
}

// ----------------------- GEMM 64x64 tile: C = A * W^T -----------------------
template <int ACT>
__global__ __launch_bounds__(256) void gemm_hl(
    const unsigned short* __restrict__ Ah, const unsigned short* __restrict__ Al,
    int lda,
    const unsigned short* __restrict__ Wh, const unsigned short* __restrict__ Wl,
    long woff,
    float* __restrict__ Cf, long zstride,
    const void* __restrict__ bias, long boff, const int* __restrict__ flag,
    int N, int K, int Kc)
{
    const int isbf = *flag;
    __shared__ __align__(16) unsigned short As[2][64][40];
    __shared__ __align__(16) unsigned short Ws[2][64][40];

    const int m0 = blockIdx.x * 64, n0 = blockIdx.y * 64;
    const int kb = blockIdx.z * Kc;
    const int t = threadIdx.x;
    const int lane = t & 63, wave = t >> 6;
    const int wm = (wave & 1) * 32, wn = (wave >> 1) * 32;
    const int srow = t >> 2, scol = (t & 3) * 8;

    const unsigned short* ah = Ah + (size_t)(m0 + srow) * lda + scol;
    const unsigned short* al = Al + (size_t)(m0 + srow) * lda + scol;
    const unsigned short* wh = Wh + woff + (size_t)(n0 + srow) * K + scol;
    const unsigned short* wl = Wl + woff + (size_t)(n0 + srow) * K + scol;

    f32x4 acc[2][2] = {};

    uint4 r0, r1, r2, r3;
#define LD64(K0) do { \
        r0 = *(const uint4*)(ah + (K0)); \
        r1 = *(const uint4*)(al + (K0)); \
        r2 = *(const uint4*)(wh + (K0)); \
        r3 = *(const uint4*)(wl + (K0)); \
    } while (0)
#define ST64() do { \
        *(uint4*)(&As[0][srow][scol]) = r0; \
        *(uint4*)(&As[1][srow][scol]) = r1; \
        *(uint4*)(&Ws[0][srow][scol]) = r2; \
        *(uint4*)(&Ws[1][srow][scol]) = r3; \
    } while (0)

    LD64(kb);
    ST64();
    __syncthreads();

    for (int k0 = kb; k0 < kb + Kc; k0 += 32) {
        const int more = (k0 + 32 < kb + Kc);
        if (more) LD64(k0 + 32);

        const int fm = lane & 15, fk = (lane >> 4) * 8;
        bf16x8 a0h = *(const bf16x8*)(&As[0][wm + fm][fk]);
        bf16x8 a1h = *(const bf16x8*)(&As[0][wm + 16 + fm][fk]);
        bf16x8 w0h = *(const bf16x8*)(&Ws[0][wn + fm][fk]);
        bf16x8 w1h = *(const bf16x8*)(&Ws[0][wn + 16 + fm][fk]);
        bf16x8 a0l = *(const bf16x8*)(&As[1][wm + fm][fk]);
        bf16x8 a1l = *(const bf16x8*)(&As[1][wm + 16 + fm][fk]);
        bf16x8 w0l = *(const bf16x8*)(&Ws[1][wn + fm][fk]);
        bf16x8 w1l = *(const bf16x8*)(&Ws[1][wn + 16 + fm][fk]);

        acc[0][0] = __builtin_amdgcn_mfma_f32_16x16x32_bf16(a0h, w0h, acc[0][0], 0, 0, 0);
        acc[0][1] = __builtin_amdgcn_mfma_f32_16x16x32_bf16(a0h, w1h, acc[0][1], 0, 0, 0);
        acc[1][0] = __builtin_amdgcn_mfma_f32_16x16x32_bf16(a1h, w0h, acc[1][0], 0, 0, 0);
        acc[1][1] = __builtin_amdgcn_mfma_f32_16x16x32_bf16(a1h, w1h, acc[1][1], 0, 0, 0);
        acc[0][0] = __builtin_amdgcn_mfma_f32_16x16x32_bf16(a0h, w0l, acc[0][0], 0, 0, 0);
        acc[0][1] = __builtin_amdgcn_mfma_f32_16x16x32_bf16(a0h, w1l, acc[0][1], 0, 0, 0);
        acc[1][0] = __builtin_amdgcn_mfma_f32_16x16x32_bf16(a1h, w0l, acc[1][0], 0, 0, 0);
        acc[1][1] = __builtin_amdgcn_mfma_f32_16x16x32_bf16(a1h, w1l, acc[1][1], 0, 0, 0);
        acc[0][0] = __builtin_amdgcn_mfma_f32_16x16x32_bf16(a0l, w0h, acc[0][0], 0, 0, 0);
        acc[0][1] = __builtin_amdgcn_mfma_f32_16x16x32_bf16(a0l, w1h, acc[0][1], 0, 0, 0);
        acc[1][0] = __builtin_amdgcn_mfma_f32_16x16x32_bf16(a1l, w0h, acc[1][0], 0, 0, 0);
        acc[1][1] = __builtin_amdgcn_mfma_f32_16x16x32_bf16(a1l, w1h, acc[1][1], 0, 0, 0);

        if (more) {
            __syncthreads();
            ST64();
            __syncthreads();
        }
    }
#undef LD64
#undef ST64

    float* Cp = Cf + (size_t)blockIdx.z * zstride;
    const int col = lane & 15, rb = (lane >> 4) * 4;
#pragma unroll
    for (int mi = 0; mi < 2; ++mi)
#pragma unroll
        for (int ni = 0; ni < 2; ++ni)
#pragma unroll
            for (int r = 0; r < 4; ++r) {
                int gm = m0 + wm + mi * 16 + rb + r;
                int gn = n0 + wn + ni * 16 + col;
                float v = acc[mi][ni][r];
                if (bias) v += ldin(bias, boff + gn, isbf);
                if (ACT == 1) v = softplus_f(v);
                Cp[(size_t)gm * N + gn] = v;
            }
}

// ------------------- RMSNorm(h + pos) -> pre-split bf16 ---------------------
__global__ __launch_bounds__(256) void rmsnorm_k(
    const void* __restrict__ hsrc, int hdyn, const void* __restrict__ pos,
    const void* __restrict__ nw, const int* __restrict__ flag,
    unsigned short* __restrict__ xnh, unsigned short* __restrict__ xnl)
{
    const int isbf = *flag;
    const int row = blockIdx.x;
    const int t = threadIdx.x;
    const size_t base = (size_t)row * 512;
    float h0 = hdyn ? ldin(hsrc, base + t, isbf)       : ((const float*)hsrc)[base + t];
    float h1 = hdyn ? ldin(hsrc, base + 256 + t, isbf) : ((const float*)hsrc)[base + 256 + t];
    float v0 = h0 + ldin(pos, base + t, isbf);
    float v1 = h1 + ldin(pos, base + 256 + t, isbf);
    float ss = v0 * v0 + v1 * v1;
#pragma unroll
    for (int o = 32; o; o >>= 1) ss += __shfl_xor(ss, o, 64);
    __shared__ float sw[4];
    if ((t & 63) == 0) sw[t >> 6] = ss;
    __syncthreads();
    float tot = sw[0] + sw[1] + sw[2] + sw[3];
    float sc = rsqrtf(tot * (1.0f / 512.0f) + 1.1920929e-07f);
    float o0 = v0 * sc * ldin(nw, t, isbf);
    float o1 = v1 * sc * ldin(nw, 256 + t, isbf);
    unsigned short hh, ll;
    split2(o0, hh, ll); xnh[base + t] = hh;       xnl[base + t] = ll;
    split2(o1, hh, ll); xnh[base + 256 + t] = hh; xnl[base + 256 + t] = ll;
}

// ------- causal depthwise conv (k=4) + SiLU -> fp32 u + pre-split bf16 ------
__global__ __launch_bounds__(256) void conv_silu_k(
    const float* __restrict__ xz,
    const void* __restrict__ cw, long cwoff,
    const void* __restrict__ cb, long cboff,
    const int* __restrict__ flag,
    float* __restrict__ xi,
    unsigned short* __restrict__ xih, unsigned short* __restrict__ xil)
{
    const int isbf = *flag;
    int g = blockIdx.x * 256 + threadIdx.x;   // T*E = 2M
    int e = g & 1023;
    int l = (g >> 10) & 1023;
    int b = g >> 20;
    float acc = ldin(cb, cboff + e, isbf);
#pragma unroll
    for (int k = 0; k < 4; ++k) {
        int ls = l - 3 + k;
        if (ls >= 0)
            acc += ldin(cw, cwoff + e * 4 + k, isbf) *
                   xz[((size_t)(b * 1024 + ls)) * 2048 + e];
    }
    acc = acc / (1.f + __expf(-acc));         // SiLU
    xi[g] = acc;
    unsigned short hh, ll;
    split2(acc, hh, ll);
    xih[g] = hh; xil[g] = ll;
}

// --------------------- selective scan, chunked (64 x 16) --------------------
#define CL 16
#define NCH 64

// Fused: split-K reduce of x_proj partials -> dbc; dt_proj (fp32 VALU dot,
// coalesced k-major weights) + bias + softplus -> dtf; chunk scan -> S, Dsum.
// launch_bounds(256,1): grid is 2 blocks/CU, so allow full VGPR budget —
// wk[32]+Aen[16]+uv[16]+Sn[16] must stay in registers (R3 fix; was VGPR=40).
__global__ __launch_bounds__(256, 1) void xp_dt_scan1(
    const float* __restrict__ Pxp,
    const float* __restrict__ dtwT, long dtwoff,
    const void* __restrict__ dtb, long dtboff,
    const float* __restrict__ AenT, long aoff,
    const float* __restrict__ xi,
    const int* __restrict__ flag,
    float* __restrict__ dbc, float* __restrict__ dtf,
    float* __restrict__ S, float* __restrict__ Dsum)
{
    const int isbf = *flag;
    const int tid = threadIdx.x;
    const int c = blockIdx.x, eg = blockIdx.y, b = blockIdx.z;
    const int t0 = b * 1024 + c * CL;

    __shared__ float red[CL][64];             // reduced dbc rows for this chunk

    // Phase A: reduce Pxp (8 z-slices) for 16 rows x 64 cols.
    for (int idx = tid; idx < CL * 64; idx += 256) {
        int ti = idx >> 6, n = idx & 63;
        float s = 0.f;
#pragma unroll
        for (int z = 0; z < 8; ++z)
            s += Pxp[(size_t)z * 131072 + (size_t)(t0 + ti) * 64 + n];
        red[ti][n] = s;
        if (eg == 0) dbc[(size_t)(t0 + ti) * 64 + n] = s;
    }

    const int e = eg * 256 + tid;

    // Batch preloads (coalesced; independent of red, overlap with Phase A).
    float wk[32];
#pragma unroll
    for (int k = 0; k < 32; ++k) wk[k] = dtwT[dtwoff + (size_t)k * 1024 + e];
    const float bias = ldin(dtb, dtboff + e, isbf);
    float Aen[16];
#pragma unroll
    for (int n = 0; n < 16; ++n) Aen[n] = AenT[aoff + (size_t)n * 1024 + e];
    float uv[CL];
#pragma unroll
    for (int i = 0; i < CL; ++i) uv[i] = xi[(size_t)(t0 + i) * 1024 + e];

    __syncthreads();

    // Phase B+C: per time-step dt dot (fp32) then scan update.
    float Sn[16];
#pragma unroll
    for (int n = 0; n < 16; ++n) Sn[n] = 0.f;
    float ds = 0.f;
#pragma unroll
    for (int i = 0; i < CL; ++i) {
        const float4* rp = (const float4*)&red[i][0];
        float acc = bias;
#pragma unroll
        for (int k4 = 0; k4 < 8; ++k4) {
            float4 r4 = rp[k4];
            acc += r4.x * wk[k4 * 4 + 0] + r4.y * wk[k4 * 4 + 1]
                 + r4.z * wk[k4 * 4 + 2] + r4.w * wk[k4 * 4 + 3];
        }
        float d = softplus_f(acc);
        dtf[(size_t)(t0 + i) * 1024 + e] = d;
        ds += d;
        float du = d * uv[i];
        const float4* Bp = (const float4*)&red[i][32];
        float4 b0 = Bp[0], b1 = Bp[1], b2 = Bp[2], b3 = Bp[3];
        float Bt[16] = {b0.x,b0.y,b0.z,b0.w, b1.x,b1.y,b1.z,b1.w,
                        b2.x,b2.y,b2.z,b2.w, b3.x,b3.y,b3.z,b3.w};
#pragma unroll
        for (int n = 0; n < 16; ++n) {
            float a = __expf(d * Aen[n]);
            Sn[n] = a * Sn[n] + du * Bt[n];
        }
    }
    size_t ob = ((size_t)(b * NCH + c) * 16) * 1024 + e;
#pragma unroll
    for (int n = 0; n < 16; ++n) S[ob + (size_t)n * 1024] = Sn[n];
    Dsum[(size_t)(b * NCH + c) * 1024 + e] = ds;
}

// cross-chunk combine: decay recomputed from Dsum (one exp per step).
__global__ __launch_bounds__(256, 1) void scan_stage2(
    const float* __restrict__ S, const float* __restrict__ Dsum,
    const float* __restrict__ AenT, long aoff,
    float* __restrict__ H0)
{
    int g = blockIdx.x * 256 + threadIdx.x;   // 32768: e + 1024n + 16384b
    int e = g & 1023, n = (g >> 10) & 15, b = g >> 14;
    const float Aen = AenT[aoff + (size_t)n * 1024 + e];
    float H = 0.f;
    for (int cb = 0; cb < NCH; cb += 8) {
        float s[8], pj[8];
#pragma unroll
        for (int j = 0; j < 8; ++j) {
            size_t idx = ((size_t)(b * NCH + cb + j) * 16 + n) * 1024 + e;
            s[j] = S[idx];
            pj[j] = __expf(Dsum[(size_t)(b * NCH + cb + j) * 1024 + e] * Aen);
        }
#pragma unroll
        for (int j = 0; j < 8; ++j) {
            size_t idx = ((size_t)(b * NCH + cb + j) * 16 + n) * 1024 + e;
            H0[idx] = H;
            H = pj[j] * H + s[j];
        }
    }
}

// final sweep: y = sum_n C*h + u*D, gate with silu(z); emit pre-split bf16.
__global__ __launch_bounds__(256, 1) void scan_stage3(
    const float* __restrict__ dtp, const float* __restrict__ u,
    const float* __restrict__ dbc,
    const float* __restrict__ AenT, long aoff,
    const void* __restrict__ Dv, long doff,
    const int* __restrict__ flag,
    const float* __restrict__ xz, const float* __restrict__ H0,
    unsigned short* __restrict__ yh, unsigned short* __restrict__ yl)
{
    const int isbf = *flag;
    int g = blockIdx.x * 256 + threadIdx.x;   // 131072
    int e = g & 1023, c = (g >> 10) & (NCH - 1), b = g >> 16;
    int t0 = b * 1024 + c * CL;

    float dv[CL], uv[CL], zv[CL];
#pragma unroll
    for (int i = 0; i < CL; ++i) {
        dv[i] = dtp[(size_t)(t0 + i) * 1024 + e];
        uv[i] = u[(size_t)(t0 + i) * 1024 + e];
        zv[i] = xz[(size_t)(t0 + i) * 2048 + 1024 + e];
    }

    float Aen[16], h[16];
    size_t ob = ((size_t)(b * NCH + c) * 16) * 1024 + e;
#pragma unroll
    for (int n = 0; n < 16; ++n) {
        Aen[n] = AenT[aoff + (size_t)n * 1024 + e];
        h[n] = H0[ob + (size_t)n * 1024];
    }
    float De = ldin(Dv, doff + e, isbf);
#pragma unroll
    for (int i = 0; i < CL; ++i) {
        float d = dv[i], uu = uv[i], du = d * uu;
        const float4* Bp = (const float4*)(dbc + (size_t)(t0 + i) * 64 + 32);
        float4 b0 = Bp[0], b1 = Bp[1], b2 = Bp[2], b3 = Bp[3];
        float4 c0 = Bp[4], c1 = Bp[5], c2 = Bp[6], c3 = Bp[7];
        float Bt[16] = {b0.x,b0.y,b0.z,b0.w, b1.x,b1.y,b1.z,b1.w,
                        b2.x,b2.y,b2.z,b2.w, b3.x,b3.y,b3.z,b3.w};
        float Ct[16] = {c0.x,c0.y,c0.z,c0.w, c1.x,c1.y,c1.z,c1.w,
                        c2.x,c2.y,c2.z,c2.w, c3.x,c3.y,c3.z,c3.w};
        float y = 0.f;
#pragma unroll
        for (int n = 0; n < 16; ++n) {
            float a = __expf(d * Aen[n]);
            h[n] = a * h[n] + du * Bt[n];
            y += h[n] * Ct[n];
        }
        float sz = zv[i] / (1.f + __expf(-zv[i]));
        float yv = (y + uu * De) * sz;
        unsigned short hh, ll;
        split2(yv, hh, ll);
        yh[(size_t)(t0 + i) * 1024 + e] = hh;
        yl[(size_t)(t0 + i) * 1024 + e] = ll;
    }
}

// ------------------------------- launcher -----------------------------------
extern "C" void kernel_launch(void* const* d_in, const int* in_sizes, int n_in,
                              void* d_out, int out_size, void* d_ws, size_t ws_size,
                              hipStream_t stream)
{
    const void* x    = d_in[0];
    const void* pos  = d_in[1];
    const void* nw   = d_in[2];
    const void* ipw  = d_in[3];   // (6,2048,512)
    const void* cw   = d_in[4];   // (6,1024,4)
    const void* cb   = d_in[5];   // (6,1024)
    const void* xpw  = d_in[6];   // (6,64,1024)
    const void* dtw  = d_in[7];   // (6,1024,32)
    const void* dtb  = d_in[8];   // (6,1024)
    const void* alog = d_in[9];   // (6,1024,16)
    const void* Dw   = d_in[10];  // (6,1024)
    const void* ow   = d_in[11];  // (6,512,1024)

    char* w = (char*)d_ws;
    auto take = [&](size_t bytes) { char* p = w; w += (bytes + 255) & ~255ull; return p; };

    float* h    = (float*)take(2048ull * 512 * 4);
    float* xz   = (float*)take(2048ull * 2048 * 4);
    float* xi   = (float*)take(2048ull * 1024 * 4);
    float* dtf  = (float*)take(2048ull * 1024 * 4);
    float* dbc  = (float*)take(2048ull * 64 * 4);
    float* S    = (float*)take(2ull * NCH * 16 * 1024 * 4);   // 8 MB
    float* H0   = (float*)take(2ull * NCH * 16 * 1024 * 4);   // 8 MB
    float* Dsum = (float*)take(2ull * NCH * 1024 * 4);        // 0.5 MB
    float* Pxp  = (float*)take(8ull * 2048 * 64 * 4);
    float* dtwT = (float*)take(6ull * 32 * 1024 * 4);
    float* AenT = (float*)take(6ull * 16 * 1024 * 4);
    unsigned short* xnh = (unsigned short*)take(2048ull * 512 * 2);
    unsigned short* xnl = (unsigned short*)take(2048ull * 512 * 2);
    unsigned short* xih = (unsigned short*)take(2048ull * 1024 * 2);
    unsigned short* xil = (unsigned short*)take(2048ull * 1024 * 2);
    unsigned short* yh  = (unsigned short*)take(2048ull * 1024 * 2);
    unsigned short* yl  = (unsigned short*)take(2048ull * 1024 * 2);
    unsigned short* wip_h = (unsigned short*)take(6ull * 2048 * 512 * 2);
    unsigned short* wip_l = (unsigned short*)take(6ull * 2048 * 512 * 2);
    unsigned short* wow_h = (unsigned short*)take(6ull * 512 * 1024 * 2);
    unsigned short* wow_l = (unsigned short*)take(6ull * 512 * 1024 * 2);
    unsigned short* wxp_h = (unsigned short*)take(6ull * 64 * 1024 * 2);
    unsigned short* wxp_l = (unsigned short*)take(6ull * 64 * 1024 * 2);
    int* flag = (int*)take(256);

    wsplit_all<<<(S1 + S2 + S3 + S4 + S5 + 255) / 256, 256, 0, stream>>>(
        ipw, ow, xpw, dtw, alog, Dw,
        wip_h, wip_l, wow_h, wow_l, wxp_h, wxp_l, dtwT, AenT, flag);

    for (int l = 0; l < 6; ++l) {
        // rmsnorm(h + pos): layer 0 reads x (dynamic dtype), else fp32 h
        rmsnorm_k<<<2048, 256, 0, stream>>>(
            l == 0 ? x : (const void*)h, l == 0 ? 1 : 0, pos, nw, flag, xnh, xnl);
        // in_proj: (T,512) x (2048,512)^T -> xz (T,2048), 128x128 tile
        gemm128<<<dim3(16, 16), 256, 0, stream>>>(
            xnh, xnl, 512, wip_h, wip_l, (long)l * 2048 * 512, xz, 2048, 512);
        conv_silu_k<<<8192, 256, 0, stream>>>(xz, cw, (long)l * 4096, cb, (long)l * 1024,
                                              flag, xi, xih, xil);
        // x_proj: (T,1024) x (64,1024)^T, split-K x8 -> Pxp
        gemm_hl<0><<<dim3(32, 1, 8), 256, 0, stream>>>(
            xih, xil, 1024, wxp_h, wxp_l, (long)l * 64 * 1024,
            Pxp, 2048l * 64, nullptr, 0, flag, 64, 1024, 128);
        // fused: reduce + dt_proj(fp32) + chunk scan -> dbc, dtf, S, Dsum
        xp_dt_scan1<<<dim3(NCH, 4, 2), 256, 0, stream>>>(
            Pxp, dtwT, (long)l * 32768, dtb, (long)l * 1024,
            AenT, (long)l * 16384, xi, flag, dbc, dtf, S, Dsum);
        scan_stage2<<<128, 256, 0, stream>>>(S, Dsum, AenT, (long)l * 16384, H0);
        scan_stage3<<<512, 256, 0, stream>>>(dtf, xi, dbc, AenT, (long)l * 16384,
                                             Dw, (long)l * 1024, flag, xz, H0, yh, yl);
        // out_proj: (T,1024) x (512,1024)^T -> h (T,512); last layer -> d_out
        float* outp = (l < 5) ? h : (float*)d_out;
        gemm_hl<0><<<dim3(32, 8), 256, 0, stream>>>(
            yh, yl, 1024, wow_h, wow_l, (long)l * 512 * 1024,
            outp, 0, nullptr, 0, flag, 512, 1024, 1024);
    }
}